// Round 3
// baseline (336.117 us; speedup 1.0000x reference)
//
#include <hip/hip_runtime.h>
#include <hip/hip_bf16.h>
#include <cstddef>
#include <cstdint>

// Problem constants
#define B_  4
#define T_  4096
#define D_  1024
#define H_  16
#define DH_ 64
#define R_  256
#define BT_ (B_ * T_)       // 16384
#define TWO_D_ (2 * D_)     // 2048

typedef __attribute__((ext_vector_type(8))) short short8;
typedef __attribute__((ext_vector_type(4))) float f32x4;

__device__ __forceinline__ float elu1(float x) {
    return x > 0.0f ? x + 1.0f : __expf(x);
}

__device__ __forceinline__ float bf2f(short u) {
    union { uint32_t i; float f; } c;
    c.i = ((uint32_t)(uint16_t)u) << 16;
    return c.f;
}

typedef __attribute__((address_space(1))) void void_g;
typedef __attribute__((address_space(3))) void void_l;
__device__ __forceinline__ void gld_lds16(const void* g, void* l) {
    __builtin_amdgcn_global_load_lds(
        (const void_g*)(uintptr_t)g,
        (void_l*)(uint32_t)(uintptr_t)l,
        16, 0, 0);
}

__device__ __forceinline__ void store_out(float* p, float v) { *p = v; }
__device__ __forceinline__ void store_out(__hip_bfloat16* p, float v) { *p = __float2bfloat16(v); }

// ---------------------------------------------------------------------------
// 256x256 phased GEMM (T2+T3+T4+T5).  C[M,N] = A[M,K] @ Bt[N,K]^T + bias.
// 512 thr = 8 waves (2M x 4N), per-wave 128x64.  BK=32, 4-slot LDS ring
// (128 KiB), stage-ahead 2 K-steps, counted vmcnt(6) (tail 4 -> 0), two
// phases per K-step (M-half quadrants, 16 MFMA each), XOR-4 LDS swizzle
// applied to BOTH the global source and the ds_read (rule #21), setprio
// around MFMA clusters.  Barriers are __builtin_amdgcn_s_barrier() (proper
// convergent intrinsic), waitcnt as separate asm — the verified-template
// idiom.
// vm accounting (per wave, 4 loads/step issued 2@q0(A) + 2@q1(B)):
//   at q0(kt) after issuing A(kt+2): outstanding = {A,B}(kt+1) + A(kt+2) = 6
//   vmcnt(6) retires everything older == step kt's 4 loads.  Slot being
//   staged = (kt+2)&3; last read at step kt-2, separated by >=2 barriers.
// ---------------------------------------------------------------------------
#define PBM 256
#define PBN 256
#define PBK 32

template<int EPI, bool BROW, typename OT>
__global__ __launch_bounds__(512, 2) void gemm_p2(
    const __hip_bfloat16* __restrict__ A,
    const __hip_bfloat16* __restrict__ Bt,
    const float* __restrict__ bias,
    OT* __restrict__ C,
    int M, int N, int K)
{
    __shared__ alignas(16) __hip_bfloat16 sm[2 * 4 * PBM * PBK];  // 128 KiB
    __hip_bfloat16* Asm = sm;
    __hip_bfloat16* Bsm = sm + 4 * PBM * PBK;

    // strip swizzle: strips of sh row-tiles, col-major within strip
    const int nbx = N / PBN;
    const int nbm = M / PBM;
    const int sh = (nbm < 8) ? nbm : 8;
    const int id = blockIdx.x;
    const int strip = id / (sh * nbx);
    const int wi = id % (sh * nbx);
    const int bm = (strip * sh + (wi % sh)) * PBM;
    const int bn = (wi / sh) * PBN;

    const int tid  = threadIdx.x;
    const int lane = tid & 63;
    const int w    = tid >> 6;
    const int wm   = w >> 2;        // 0..1
    const int wn   = w & 3;         // 0..3
    const int r15  = lane & 15;
    const int kg   = lane >> 4;

    // staging: chunk c in [0,1024): row=c>>2, phys slot u=c&3 holds logical
    // k-group g = u ^ (row&3).  Source address pre-swizzled accordingly.
    const int c0 = tid, c1 = tid + 512;
    const int rA0 = c0 >> 2, rA1 = c1 >> 2;
    const int gA0 = (c0 & 3) ^ (rA0 & 3), gA1 = (c1 & 3) ^ (rA1 & 3);
    const __hip_bfloat16* a0 = A  + (size_t)(bm + rA0) * K + gA0 * 8;
    const __hip_bfloat16* a1 = A  + (size_t)(bm + rA1) * K + gA1 * 8;
    const __hip_bfloat16* b0 = Bt + (size_t)(bn + rA0) * K + gA0 * 8;
    const __hip_bfloat16* b1 = Bt + (size_t)(bn + rA1) * K + gA1 * 8;

    auto stageA = [&](int t) {
        __hip_bfloat16* d = Asm + (t & 3) * (PBM * PBK);
        gld_lds16(a0 + t * PBK, d + c0 * 8);
        gld_lds16(a1 + t * PBK, d + c1 * 8);
    };
    auto stageB = [&](int t) {
        __hip_bfloat16* d = Bsm + (t & 3) * (PBM * PBK);
        gld_lds16(b0 + t * PBK, d + c0 * 8);
        gld_lds16(b1 + t * PBK, d + c1 * 8);
    };

    const int nk = K / PBK;   // >= 8 for all call sites
    f32x4 acc[8][4] = {};

    stageA(0); stageB(0); stageA(1); stageB(1);

    for (int kt = 0; kt < nk; ++kt) {
        const __hip_bfloat16* As_ = Asm + (kt & 3) * (PBM * PBK);
        const __hip_bfloat16* Bs_ = Bsm + (kt & 3) * (PBM * PBK);

        // ---- phase 0: stage A(kt+2) | counted wait | A-half0 x B ----
        if (kt + 2 < nk) {
            stageA(kt + 2);
            asm volatile("s_waitcnt vmcnt(6)" ::: "memory");
        } else if (kt + 2 == nk) {
            asm volatile("s_waitcnt vmcnt(4)" ::: "memory");
        } else {
            asm volatile("s_waitcnt vmcnt(0)" ::: "memory");
        }
        __builtin_amdgcn_s_barrier();

        short8 af[8], bf[4];
#pragma unroll
        for (int i = 0; i < 4; ++i) {
            const int r = wm * 128 + i * 16 + r15;
            af[i] = *(const short8*)(As_ + r * PBK + ((kg ^ (r & 3)) * 8));
        }
#pragma unroll
        for (int j = 0; j < 4; ++j) {
            const int r = wn * 64 + j * 16 + r15;
            bf[j] = *(const short8*)(Bs_ + r * PBK + ((kg ^ (r & 3)) * 8));
        }
        __builtin_amdgcn_s_setprio(1);
#pragma unroll
        for (int i = 0; i < 4; ++i)
#pragma unroll
            for (int j = 0; j < 4; ++j)
                acc[i][j] = __builtin_amdgcn_mfma_f32_16x16x32_bf16(af[i], bf[j], acc[i][j], 0, 0, 0);
        __builtin_amdgcn_s_setprio(0);
        __builtin_amdgcn_s_barrier();

        // ---- phase 1: stage B(kt+2) | A-half1 x B ----
        if (kt + 2 < nk) stageB(kt + 2);
#pragma unroll
        for (int i = 4; i < 8; ++i) {
            const int r = wm * 128 + i * 16 + r15;
            af[i] = *(const short8*)(As_ + r * PBK + ((kg ^ (r & 3)) * 8));
        }
        __builtin_amdgcn_s_setprio(1);
#pragma unroll
        for (int i = 4; i < 8; ++i)
#pragma unroll
            for (int j = 0; j < 4; ++j)
                acc[i][j] = __builtin_amdgcn_mfma_f32_16x16x32_bf16(af[i], bf[j], acc[i][j], 0, 0, 0);
        __builtin_amdgcn_s_setprio(0);
        __builtin_amdgcn_s_barrier();
    }

    // epilogue; C/D layout: col=lane&15, row=(lane>>4)*4+reg  [m89-verified]
    const int row0 = bm + wm * 128 + (lane >> 4) * 4;

    float brow[8][4];
    if (BROW) {
#pragma unroll
        for (int i = 0; i < 8; ++i)
#pragma unroll
            for (int r = 0; r < 4; ++r) brow[i][r] = bias[row0 + i * 16 + r];
    }
#pragma unroll
    for (int j = 0; j < 4; ++j) {
        const int col = bn + wn * 64 + j * 16 + r15;
        const float bv = BROW ? 0.0f : bias[col];
        const bool kp_col = ((col & 127) < 64);
#pragma unroll
        for (int i = 0; i < 8; ++i) {
#pragma unroll
            for (int r = 0; r < 4; ++r) {
                const int row = row0 + i * 16 + r;
                float v = acc[i][j][r] + (BROW ? brow[i][r] : bv);
                if (EPI == 1) v = elu1(v);
                else if (EPI == 2) {
                    const bool kp = BROW ? ((row & 127) < 64) : kp_col;
                    if (kp) v = elu1(v);
                }
                store_out(C + (size_t)row * N + col, v);
            }
        }
    }
}

// ---------------------------------------------------------------------------
// OLD 128x128 ring GEMM (hardware-validated round 1) — kept for xd (N=256).
// ---------------------------------------------------------------------------
#define BM 128
#define BN 128
#define BK 32
#define NBUF 5

template<int EPI, bool BROW, typename OT>
__global__ __launch_bounds__(256) void gemm_bf16(
    const __hip_bfloat16* __restrict__ A,
    const __hip_bfloat16* __restrict__ Bt,
    const float* __restrict__ bias,
    OT* __restrict__ C,
    OT* __restrict__ C2,
    int M, int N, int K)
{
    __shared__ alignas(16) __hip_bfloat16 As[NBUF * BM * BK];
    __shared__ alignas(16) __hip_bfloat16 Bs[NBUF * BN * BK];

    const int nbx = N / BN;
    const int id = blockIdx.x;
    const int strip = id / (8 * nbx);
    const int wi = id % (8 * nbx);
    const int bm = (strip * 8 + (wi & 7)) * BM;
    const int bn = (wi >> 3) * BN;

    const int tid  = threadIdx.x;
    const int lane = tid & 63;
    const int wm   = (tid >> 7) * 64;
    const int wn   = ((tid >> 6) & 1) * 64;
    const int r15  = lane & 15;
    const int kg   = lane >> 4;

    f32x4 acc[4][4] = {};

    const int c0 = tid, c1 = tid + 256;
    const __hip_bfloat16* a0 = A  + (size_t)(bm + (c0 >> 2)) * K + (c0 & 3) * 8;
    const __hip_bfloat16* a1 = A  + (size_t)(bm + (c1 >> 2)) * K + (c1 & 3) * 8;
    const __hip_bfloat16* b0 = Bt + (size_t)(bn + (c0 >> 2)) * K + (c0 & 3) * 8;
    const __hip_bfloat16* b1 = Bt + (size_t)(bn + (c1 >> 2)) * K + (c1 & 3) * 8;

    const int nk = K / BK;

    auto stage = [&](int t) {
        const int buf = t % NBUF;
        __hip_bfloat16* Ad = As + buf * (BM * BK);
        __hip_bfloat16* Bd = Bs + buf * (BN * BK);
        const int k0 = t * BK;
        gld_lds16(a0 + k0, Ad + c0 * 8);
        gld_lds16(a1 + k0, Ad + c1 * 8);
        gld_lds16(b0 + k0, Bd + c0 * 8);
        gld_lds16(b1 + k0, Bd + c1 * 8);
    };

    stage(0); stage(1); stage(2);

    for (int t = 0; t < nk; ++t) {
        if (t + 3 < nk) {
            stage(t + 3);
            asm volatile("s_waitcnt vmcnt(12)\ns_barrier" ::: "memory");
        } else if (t + 2 < nk) {
            asm volatile("s_waitcnt vmcnt(8)\ns_barrier" ::: "memory");
        } else if (t + 1 < nk) {
            asm volatile("s_waitcnt vmcnt(4)\ns_barrier" ::: "memory");
        } else {
            asm volatile("s_waitcnt vmcnt(0)\ns_barrier" ::: "memory");
        }

        const __hip_bfloat16* Asb = As + (t % NBUF) * (BM * BK);
        const __hip_bfloat16* Bsb = Bs + (t % NBUF) * (BN * BK);

        short8 af[4], bf[4];
#pragma unroll
        for (int i = 0; i < 4; ++i) {
            af[i] = *(const short8*)(Asb + (wm + i * 16 + r15) * BK + kg * 8);
            bf[i] = *(const short8*)(Bsb + (wn + i * 16 + r15) * BK + kg * 8);
        }
#pragma unroll
        for (int i = 0; i < 4; ++i)
#pragma unroll
            for (int j = 0; j < 4; ++j)
                acc[i][j] = __builtin_amdgcn_mfma_f32_16x16x32_bf16(af[i], bf[j], acc[i][j], 0, 0, 0);
    }

    const int row0 = bm + wm + (lane >> 4) * 4;

    if (EPI == 3) {
        const bool qreg = (bn < 1024);
#pragma unroll
        for (int j = 0; j < 4; ++j) {
            const int col = bn + wn + j * 16 + r15;
            const float bv = bias[col];
#pragma unroll
            for (int i = 0; i < 4; ++i)
#pragma unroll
                for (int r = 0; r < 4; ++r) {
                    const int row = row0 + i * 16 + r;
                    float v = acc[i][j][r] + bv;
                    if (qreg) {
                        store_out(C + (size_t)row * 1024 + col, elu1(v));
                    } else {
                        store_out(C2 + (size_t)row * 256 + (col - 1024), v);
                    }
                }
        }
        return;
    }

    float brow[4][4];
    if (BROW) {
#pragma unroll
        for (int i = 0; i < 4; ++i)
#pragma unroll
            for (int r = 0; r < 4; ++r) brow[i][r] = bias[row0 + i * 16 + r];
    }
#pragma unroll
    for (int j = 0; j < 4; ++j) {
        const int col = bn + wn + j * 16 + r15;
        const float bv = BROW ? 0.0f : bias[col];
        const bool kp_col = ((col & 127) < 64);
#pragma unroll
        for (int i = 0; i < 4; ++i) {
#pragma unroll
            for (int r = 0; r < 4; ++r) {
                const int row = row0 + i * 16 + r;
                float v = acc[i][j][r] + (BROW ? brow[i][r] : bv);
                if (EPI == 1) v = elu1(v);
                else if (EPI == 2) {
                    const bool kp = BROW ? ((row & 127) < 64) : kp_col;
                    if (kp) v = elu1(v);
                }
                store_out(C + (size_t)row * N + col, v);
            }
        }
    }
}

// ---------------------------------------------------------------------------
__global__ __launch_bounds__(256) void cast_bf16_kernel(
    const float* __restrict__ s, __hip_bfloat16* __restrict__ d, int n)
{
    const int i = (blockIdx.x * 256 + threadIdx.x) * 8;
    if (i >= n) return;
    float4 v0 = *(const float4*)(s + i);
    float4 v1 = *(const float4*)(s + i + 4);
    __hip_bfloat16 t[8];
    t[0] = __float2bfloat16(v0.x); t[1] = __float2bfloat16(v0.y);
    t[2] = __float2bfloat16(v0.z); t[3] = __float2bfloat16(v0.w);
    t[4] = __float2bfloat16(v1.x); t[5] = __float2bfloat16(v1.y);
    t[6] = __float2bfloat16(v1.z); t[7] = __float2bfloat16(v1.w);
    *(short8*)(d + i) = *(const short8*)t;
}

__global__ __launch_bounds__(256) void transpose_cast(
    const float* __restrict__ W, __hip_bfloat16* __restrict__ Wt, int K, int N)
{
    __shared__ float t[32][33];
    const int n0 = blockIdx.x * 32, k0 = blockIdx.y * 32;
    const int c = threadIdx.x & 31, r = threadIdx.x >> 5;
#pragma unroll
    for (int rr = r; rr < 32; rr += 8)
        t[rr][c] = W[(size_t)(k0 + rr) * N + n0 + c];
    __syncthreads();
#pragma unroll
    for (int rr = r; rr < 32; rr += 8)
        Wt[(size_t)(n0 + rr) * K + k0 + c] = __float2bfloat16(t[c][rr]);
}

// ---------------------------------------------------------------------------
// ctx_mfma: ctx[bh][d][e] = sum_t K^T[d][t] * V^T[e][t]; ksum via ones-trick.
// ---------------------------------------------------------------------------
#define CHT 512

__global__ __launch_bounds__(256) void ctx_mfma(
    const __hip_bfloat16* __restrict__ kvT, float* __restrict__ ctx,
    float* __restrict__ ksum)
{
    __shared__ alignas(16) unsigned char smem[40960];
    float* red0 = (float*)smem;
    float* red1 = (float*)(smem + 20480);

    const int bh = blockIdx.x >> 3;
    const int chunk = blockIdx.x & 7;
    const int b = bh >> 4;
    const int h = bh & 15;
    const int tid = threadIdx.x;
    const int lane = tid & 63;
    const int w = tid >> 6;
    const int r15 = lane & 15;
    const int kg  = lane >> 4;

    f32x4 acc[4][4] = {};
    f32x4 acc4[4] = {};

    const short one = (short)0x3F80;
    const short8 bfv = (r15 == 0)
        ? (short8){one, one, one, one, one, one, one, one}
        : (short8){0, 0, 0, 0, 0, 0, 0, 0};

    const size_t tbase = (size_t)b * T_ + (size_t)chunk * CHT;
    const __hip_bfloat16* src = kvT + (size_t)(h * 128) * BT_ + tbase;

    for (int it = 0; it < CHT / 128; ++it) {
#pragma unroll
        for (int r = 0; r < 8; ++r) {
            const int c = r * 256 + tid;
            const int s = c >> 9, j = (c >> 2) & 127, u = c & 3;
            gld_lds16(src + (size_t)j * BT_ + it * 128 + s * 32 + u * 8,
                      smem + c * 16);
        }
        __syncthreads();

        const __hip_bfloat16* Ls = (const __hip_bfloat16*)smem;
        short8 af[4], bf[4];
#pragma unroll
        for (int i = 0; i < 4; ++i) {
            af[i] = *(const short8*)(Ls + (w * 128 + i * 16 + r15) * 32 + kg * 8);
            bf[i] = *(const short8*)(Ls + (w * 128 + 64 + i * 16 + r15) * 32 + kg * 8);
        }
#pragma unroll
        for (int i = 0; i < 4; ++i) {
#pragma unroll
            for (int j = 0; j < 4; ++j)
                acc[i][j] = __builtin_amdgcn_mfma_f32_16x16x32_bf16(af[i], bf[j], acc[i][j], 0, 0, 0);
            acc4[i] = __builtin_amdgcn_mfma_f32_16x16x32_bf16(af[i], bfv, acc4[i], 0, 0, 0);
        }
        __syncthreads();
    }

    const int q4 = lane >> 4;
    auto wr = [&](float* reg) {
#pragma unroll
        for (int i = 0; i < 4; ++i) {
#pragma unroll
            for (int r = 0; r < 4; ++r) {
                const int row = i * 16 + q4 * 4 + r;
#pragma unroll
                for (int j = 0; j < 4; ++j) reg[row * 80 + j * 16 + r15] = acc[i][j][r];
                reg[row * 80 + 64 + r15] = acc4[i][r];
            }
        }
    };
    auto rd = [&](const float* reg) {
#pragma unroll
        for (int i = 0; i < 4; ++i) {
#pragma unroll
            for (int r = 0; r < 4; ++r) {
                const int row = i * 16 + q4 * 4 + r;
#pragma unroll
                for (int j = 0; j < 4; ++j) acc[i][j][r] += reg[row * 80 + j * 16 + r15];
                acc4[i][r] += reg[row * 80 + 64 + r15];
            }
        }
    };

    if (w == 1) wr(red0);
    if (w == 3) wr(red1);
    __syncthreads();
    if (w == 0) rd(red0);
    if (w == 2) rd(red1);
    __syncthreads();
    if (w == 2) wr(red0);
    __syncthreads();
    if (w == 0) { rd(red0); wr(red0); }
    __syncthreads();

    float* cdst = ctx + (size_t)bh * 4096;
#pragma unroll
    for (int r = 0; r < 16; ++r) {
        const int idx = r * 256 + tid;
        const int d = idx >> 6, e = idx & 63;
        atomicAdd(cdst + idx, red0[d * 80 + e]);
    }
    if (tid < 64) atomicAdd(ksum + bh * 64 + tid, red0[tid * 80 + 64]);
}

// ---------------------------------------------------------------------------
__global__ __launch_bounds__(256) void pack_ctx(
    const float* __restrict__ ctx, __hip_bfloat16* __restrict__ ctxT)
{
    __shared__ float L[64 * 65];
    const int bh = blockIdx.x;
    const int tid = threadIdx.x;
#pragma unroll
    for (int r = 0; r < 16; ++r) {
        const int idx = r * 256 + tid;
        L[(idx >> 6) * 65 + (idx & 63)] = ctx[(size_t)bh * 4096 + idx];
    }
    __syncthreads();
#pragma unroll
    for (int r = 0; r < 16; ++r) {
        const int idx = r * 256 + tid;
        ctxT[(size_t)bh * 4096 + idx] =
            __float2bfloat16(L[(idx & 63) * 65 + (idx >> 6)]);
    }
}

// ---------------------------------------------------------------------------
// out_mfma: out[t][h*64+e] = z_t * sum_d q[t][d] * ctx[d][e]
// ---------------------------------------------------------------------------
__global__ __launch_bounds__(256) void out_mfma(
    const __hip_bfloat16* __restrict__ qb, const __hip_bfloat16* __restrict__ ctxT,
    const float* __restrict__ ksum, __hip_bfloat16* __restrict__ outb)
{
    __shared__ alignas(16) unsigned char As[256 * 128];
    __shared__ alignas(16) unsigned char Bs[64 * 128];
    __shared__ float ksumL[64];
    __shared__ float zbuf[256];

    const int bh = blockIdx.x >> 4;
    const int tile = blockIdx.x & 15;
    const int b = bh >> 4;
    const int h = bh & 15;
    const int tid = threadIdx.x;
    const int lane = tid & 63;
    const int w = tid >> 6;
    const int r15 = lane & 15;
    const int kg  = lane >> 4;

    const size_t trow0 = (size_t)b * T_ + (size_t)tile * 256;

#pragma unroll
    for (int r = 0; r < 8; ++r) {
        const int c = r * 256 + tid;
        const int row = c >> 3, slot = c & 7, u = slot ^ (row & 7);
        gld_lds16(qb + (trow0 + row) * D_ + h * 64 + u * 8, As + c * 16);
    }
#pragma unroll
    for (int r = 0; r < 2; ++r) {
        const int c = r * 256 + tid;
        const int row = c >> 3, slot = c & 7, u = slot ^ (row & 7);
        gld_lds16(ctxT + (size_t)bh * 4096 + row * 64 + u * 8, Bs + c * 16);
    }
    if (tid < 64) ksumL[tid] = ksum[bh * 64 + tid];
    __syncthreads();

    short8 af[4][2], bf[4][2];
#pragma unroll
    for (int i = 0; i < 4; ++i)
#pragma unroll
        for (int s = 0; s < 2; ++s) {
            const int m = w * 64 + i * 16 + r15;
            const int n = i * 16 + r15;
            const int uk = s * 4 + kg;
            af[i][s] = *(const short8*)(As + m * 128 + ((uk ^ (m & 7)) * 16));
            bf[i][s] = *(const short8*)(Bs + n * 128 + ((uk ^ (n & 7)) * 16));
        }

    f32x4 acc[4][4] = {};
#pragma unroll
    for (int s = 0; s < 2; ++s)
#pragma unroll
        for (int i = 0; i < 4; ++i)
#pragma unroll
            for (int j = 0; j < 4; ++j)
                acc[i][j] = __builtin_amdgcn_mfma_f32_16x16x32_bf16(af[i][s], bf[j][s], acc[i][j], 0, 0, 0);

    float dsum[4];
#pragma unroll
    for (int i = 0; i < 4; ++i) {
        float s0 = 0.0f;
#pragma unroll
        for (int s = 0; s < 2; ++s)
#pragma unroll
            for (int j8 = 0; j8 < 8; ++j8)
                s0 += bf2f(af[i][s][j8]) * ksumL[s * 32 + kg * 8 + j8];
        s0 += __shfl_xor(s0, 16);
        s0 += __shfl_xor(s0, 32);
        dsum[i] = s0;
    }
    if (lane < 16) {
#pragma unroll
        for (int i = 0; i < 4; ++i)
            zbuf[w * 64 + i * 16 + lane] = 1.0f / (dsum[i] + 1e-6f);
    }
    __syncthreads();

    const int q4 = lane >> 4;
#pragma unroll
    for (int i = 0; i < 4; ++i) {
#pragma unroll
        for (int r = 0; r < 4; ++r) {
            const int m = w * 64 + i * 16 + q4 * 4 + r;
            const float z = zbuf[m];
#pragma unroll
            for (int j = 0; j < 4; ++j) {
                outb[(trow0 + m) * D_ + h * 64 + j * 16 + r15] =
                    __float2bfloat16(acc[i][j][r] * z);
            }
        }
    }
}

// ---------------------------------------------------------------------------
extern "C" void kernel_launch(void* const* d_in, const int* in_sizes, int n_in,
                              void* d_out, int out_size, void* d_ws, size_t ws_size,
                              hipStream_t stream) {
    const float* x  = (const float*)d_in[0];
    const float* Wq = (const float*)d_in[1];
    const float* bq = (const float*)d_in[2];
    const float* Wd = (const float*)d_in[3];
    const float* bd = (const float*)d_in[4];
    const float* Wu = (const float*)d_in[5];
    const float* bu = (const float*)d_in[6];
    const float* Wo = (const float*)d_in[7];
    const float* bo = (const float*)d_in[8];
    float* out = (float*)d_out;

    __hip_bfloat16* xb    = (__hip_bfloat16*)d_ws;            // BT*D
    __hip_bfloat16* WqdT  = xb    + (size_t)BT_ * D_;         // [1280][1024]
    __hip_bfloat16* WuT   = WqdT  + (size_t)1280 * D_;        // [2048][256]
    __hip_bfloat16* WoT   = WuT   + (size_t)TWO_D_ * R_;      // [1024][1024]
    __hip_bfloat16* xdb   = WoT   + (size_t)D_ * D_;          // BT*R
    __hip_bfloat16* kvT   = xdb   + (size_t)BT_ * R_;         // 2048*BT
    __hip_bfloat16* qb    = kvT   + (size_t)TWO_D_ * BT_;     // BT*D
    float* bias_qd = (float*)(qb + (size_t)BT_ * D_);         // 1280 (unused now)
    float* ctx  = bias_qd + 1280;                             // 64*4096
    float* ksum = ctx + (size_t)B_ * H_ * DH_ * DH_;          // 64*64
    __hip_bfloat16* ctxT = (__hip_bfloat16*)(ksum + B_ * H_ * DH_);  // 64*4096
    __hip_bfloat16* outb = xb;   // alias: xb dead after q/xd GEMMs

    hipMemsetAsync(ctx, 0,
        (size_t)(B_ * H_ * DH_ * DH_ + B_ * H_ * DH_) * sizeof(float), stream);

    cast_bf16_kernel<<<(BT_ * D_) / (8 * 256), 256, 0, stream>>>(x, xb, BT_ * D_);
    transpose_cast<<<dim3(D_ / 32, D_ / 32), 256, 0, stream>>>(Wq, WqdT, D_, D_);
    transpose_cast<<<dim3(R_ / 32, D_ / 32), 256, 0, stream>>>(Wd, WqdT + (size_t)D_ * D_, D_, R_);
    transpose_cast<<<dim3(TWO_D_ / 32, R_ / 32), 256, 0, stream>>>(Wu, WuT, R_, TWO_D_);
    transpose_cast<<<dim3(D_ / 32, D_ / 32), 256, 0, stream>>>(Wo, WoT, D_, D_);

    // 1) xd = x @ Wd + bd    (old 128^2 ring; grid 256 = 1 block/CU)
    gemm_bf16<0, false, __hip_bfloat16><<<(BT_ / BM) * (R_ / BN), 256, 0, stream>>>(
        xb, WqdT + (size_t)D_ * D_, bd, xdb, nullptr, BT_, R_, D_);
    // 2) q = elu1(x @ Wq + bq)   (new 256^2 phased; grid 256 = 1 block/CU)
    gemm_p2<1, false, __hip_bfloat16><<<(BT_ / PBM) * (D_ / PBN), 512, 0, stream>>>(
        xb, WqdT, bq, qb, BT_, D_, D_);
    // 3) kvT[j][t] = Wu^T @ xd^T + bu[j], elu1 on rows (j&127)<64  (grid 512)
    gemm_p2<2, true, __hip_bfloat16><<<(TWO_D_ / PBM) * (BT_ / PBN), 512, 0, stream>>>(
        WuT, xdb, bu, kvT, TWO_D_, BT_, R_);
    // 4) ctx + ksum via MFMA
    ctx_mfma<<<64 * (T_ / CHT), 256, 0, stream>>>(kvT, ctx, ksum);
    // 5) pack ctx -> bf16 transposed
    pack_ctx<<<64, 256, 0, stream>>>(ctx, ctxT);
    // 6) out = z * (q @ ctx)
    out_mfma<<<64 * 16, 256, 0, stream>>>(qb, ctxT, ksum, outb);
    // 7) final = outb @ Wo + bo   (new 256^2 phased; grid 256)
    gemm_p2<0, false, float><<<(BT_ / PBM) * (D_ / PBN), 512, 0, stream>>>(
        outb, WoT, bo, out, BT_, D_, D_);
}

// Round 5
// 332.992 us; speedup vs baseline: 1.0094x; 1.0094x over previous
//
#include <hip/hip_runtime.h>
#include <hip/hip_bf16.h>
#include <cstddef>
#include <cstdint>

// Problem constants
#define B_  4
#define T_  4096
#define D_  1024
#define H_  16
#define DH_ 64
#define R_  256
#define BT_ (B_ * T_)       // 16384
#define TWO_D_ (2 * D_)     // 2048

typedef __attribute__((ext_vector_type(8))) short short8;
typedef __attribute__((ext_vector_type(4))) float f32x4;

__device__ __forceinline__ float elu1(float x) {
    return x > 0.0f ? x + 1.0f : __expf(x);
}

__device__ __forceinline__ float bf2f(short u) {
    union { uint32_t i; float f; } c;
    c.i = ((uint32_t)(uint16_t)u) << 16;
    return c.f;
}

typedef __attribute__((address_space(1))) void void_g;
typedef __attribute__((address_space(3))) void void_l;
__device__ __forceinline__ void gld_lds16(const void* g, void* l) {
    __builtin_amdgcn_global_load_lds(
        (const void_g*)(uintptr_t)g,
        (void_l*)(uint32_t)(uintptr_t)l,
        16, 0, 0);
}

__device__ __forceinline__ void store_out(float* p, float v) { *p = v; }
__device__ __forceinline__ void store_out(__hip_bfloat16* p, float v) { *p = __float2bfloat16(v); }

// ---------------------------------------------------------------------------
// 256x256 phased GEMM v3.  C[M,N] = A[M,K] @ Bt[N,K]^T + bias.
// 512 thr = 8 waves (2M x 4N), per-wave 128x64.  BK=32, 4-slot LDS ring.
// v3 vs failed v2: B fragments are PING-PONG buffered (bfA/bfB via kt-unroll
// by 2) so P1's MFMA consumes the CURRENT tile's bf while P1's prefetch
// writes the OTHER buffer.  (v2 overwrote bf before use -> wrong results.)
// af0/af1 are read at P0; their latency hides under vmcnt+barrier.
// Swizzle: phys slot u = kg ^ ((row>>2)&3) — uniform across the 8 four-bank
// groups at 16-lane granularity (round-3's (row&3) was 4-way conflicted).
// Applied to BOTH pre-swizzled global source and ds_read (rule #21).
// Ledger per step kt (A(t) staged @P0(t-3), B(t) @P1(t-3), 2 loads each):
//  P0: stageA(kt+3); read af0,af1(slot kt); lgkm(4) [bf_cur,af0 done];
//      vmcnt(6) [tiles<=kt+1 retired; tail 4->0]; BARRIER; MFMA af0 x bf_cur.
//  P1: stageB(kt+3); read bf_next(slot kt+1) [retired @P0+BARRIER];
//      lgkm(4) [af1 done]; BARRIER; MFMA af1 x bf_cur.
//  WAR: stageA(kt+3) hits A-slot(kt-1): af reads of kt-1 drained by
//  lgkm(4)@P1(kt-1) before its barrier.  stageB(kt+3) hits B-slot(kt-1):
//  bf(kt-1) reads drained by lgkm(4)@P0(kt-1).  All collective via barriers.
// ---------------------------------------------------------------------------
#define PBM 256
#define PBN 256
#define PBK 32

template<int EPI, bool BROW, typename OT>
__global__ __launch_bounds__(512, 2) void gemm_p2(
    const __hip_bfloat16* __restrict__ A,
    const __hip_bfloat16* __restrict__ Bt,
    const float* __restrict__ bias,
    OT* __restrict__ C,
    int M, int N, int K)
{
    __shared__ alignas(16) __hip_bfloat16 sm[2 * 4 * PBM * PBK];  // 128 KiB
    __hip_bfloat16* Asm = sm;
    __hip_bfloat16* Bsm = sm + 4 * PBM * PBK;

    // strip swizzle: strips of sh row-tiles, col-major within strip
    const int nbx = N / PBN;
    const int nbm = M / PBM;
    const int sh = (nbm < 8) ? nbm : 8;
    const int id = blockIdx.x;
    const int strip = id / (sh * nbx);
    const int wi = id % (sh * nbx);
    const int bm = (strip * sh + (wi % sh)) * PBM;
    const int bn = (wi / sh) * PBN;

    const int tid  = threadIdx.x;
    const int lane = tid & 63;
    const int w    = tid >> 6;
    const int wm   = w >> 2;        // 0..1
    const int wn   = w & 3;         // 0..3
    const int r15  = lane & 15;
    const int kg   = lane >> 4;

    // staging: chunk c in [0,1024): row=c>>2, phys slot u=c&3 holds logical
    // k-group g = u ^ ((row>>2)&3).  Source address pre-swizzled accordingly.
    const int c0 = tid, c1 = tid + 512;
    const int rA0 = c0 >> 2, rA1 = c1 >> 2;
    const int gA0 = (c0 & 3) ^ ((rA0 >> 2) & 3), gA1 = (c1 & 3) ^ ((rA1 >> 2) & 3);
    const __hip_bfloat16* a0 = A  + (size_t)(bm + rA0) * K + gA0 * 8;
    const __hip_bfloat16* a1 = A  + (size_t)(bm + rA1) * K + gA1 * 8;
    const __hip_bfloat16* b0 = Bt + (size_t)(bn + rA0) * K + gA0 * 8;
    const __hip_bfloat16* b1 = Bt + (size_t)(bn + rA1) * K + gA1 * 8;

    auto stageA = [&](int t) {
        __hip_bfloat16* d = Asm + (t & 3) * (PBM * PBK);
        gld_lds16(a0 + t * PBK, d + c0 * 8);
        gld_lds16(a1 + t * PBK, d + c1 * 8);
    };
    auto stageB = [&](int t) {
        __hip_bfloat16* d = Bsm + (t & 3) * (PBM * PBK);
        gld_lds16(b0 + t * PBK, d + c0 * 8);
        gld_lds16(b1 + t * PBK, d + c1 * 8);
    };

    const int nk = K / PBK;   // even, >= 8 for all call sites
    f32x4 acc[8][4] = {};
    short8 bfA[4], bfB[4];

    // prologue: tiles 0..2 staged; tile 0 retired + collective; preload bf(0)
    stageA(0); stageB(0); stageA(1); stageB(1); stageA(2); stageB(2);
    asm volatile("s_waitcnt vmcnt(8)" ::: "memory");
    __builtin_amdgcn_s_barrier();
#pragma unroll
    for (int j = 0; j < 4; ++j) {
        const int r = wn * 64 + j * 16 + r15;
        bfA[j] = *(const short8*)(Bsm + r * PBK + ((kg ^ ((r >> 2) & 3)) * 8));
    }

    auto step = [&](int kt, short8 (&bfc)[4], short8 (&bfn)[4]) {
        const __hip_bfloat16* As_ = Asm + (kt & 3) * (PBM * PBK);
        const __hip_bfloat16* Bn_ = Bsm + ((kt + 1) & 3) * (PBM * PBK);
        short8 af0[4], af1[4];

        // ---------------- phase 0 ----------------
        if (kt + 3 < nk) stageA(kt + 3);
#pragma unroll
        for (int i = 0; i < 4; ++i) {
            const int r = wm * 128 + i * 16 + r15;
            af0[i] = *(const short8*)(As_ + r * PBK + ((kg ^ ((r >> 2) & 3)) * 8));
        }
#pragma unroll
        for (int i = 0; i < 4; ++i) {
            const int r = wm * 128 + 64 + i * 16 + r15;
            af1[i] = *(const short8*)(As_ + r * PBK + ((kg ^ ((r >> 2) & 3)) * 8));
        }
        asm volatile("s_waitcnt lgkmcnt(4)" ::: "memory");   // bf_cur, af0 ready
        if (kt + 3 < nk) {
            asm volatile("s_waitcnt vmcnt(6)" ::: "memory"); // tiles<=kt+1 done
        } else if (kt + 2 < nk) {
            asm volatile("s_waitcnt vmcnt(4)" ::: "memory");
        } else if (kt + 1 < nk) {
            asm volatile("s_waitcnt vmcnt(0)" ::: "memory");
        }
        __builtin_amdgcn_s_barrier();
        __builtin_amdgcn_s_setprio(1);
#pragma unroll
        for (int i = 0; i < 4; ++i)
#pragma unroll
            for (int j = 0; j < 4; ++j)
                acc[i][j] = __builtin_amdgcn_mfma_f32_16x16x32_bf16(af0[i], bfc[j], acc[i][j], 0, 0, 0);
        __builtin_amdgcn_s_setprio(0);

        // ---------------- phase 1 ----------------
        if (kt + 3 < nk) stageB(kt + 3);
        if (kt + 1 < nk) {
#pragma unroll
            for (int j = 0; j < 4; ++j) {
                const int r = wn * 64 + j * 16 + r15;
                bfn[j] = *(const short8*)(Bn_ + r * PBK + ((kg ^ ((r >> 2) & 3)) * 8));
            }
            asm volatile("s_waitcnt lgkmcnt(4)" ::: "memory");  // af1 ready
        } else {
            asm volatile("s_waitcnt lgkmcnt(0)" ::: "memory");
        }
        __builtin_amdgcn_s_barrier();
        __builtin_amdgcn_s_setprio(1);
#pragma unroll
        for (int i = 0; i < 4; ++i)
#pragma unroll
            for (int j = 0; j < 4; ++j)
                acc[4 + i][j] = __builtin_amdgcn_mfma_f32_16x16x32_bf16(af1[i], bfc[j], acc[4 + i][j], 0, 0, 0);
        __builtin_amdgcn_s_setprio(0);
    };

    for (int kt = 0; kt < nk; kt += 2) {
        step(kt,     bfA, bfB);
        step(kt + 1, bfB, bfA);
    }

    // epilogue; C/D layout: col=lane&15, row=(lane>>4)*4+reg  [m89-verified]
    const int row0 = bm + wm * 128 + (lane >> 4) * 4;

    float brow[8][4];
    if (BROW) {
#pragma unroll
        for (int i = 0; i < 8; ++i)
#pragma unroll
            for (int r = 0; r < 4; ++r) brow[i][r] = bias[row0 + i * 16 + r];
    }
#pragma unroll
    for (int j = 0; j < 4; ++j) {
        const int col = bn + wn * 64 + j * 16 + r15;
        const float bv = BROW ? 0.0f : bias[col];
        const bool kp_col = ((col & 127) < 64);
#pragma unroll
        for (int i = 0; i < 8; ++i) {
#pragma unroll
            for (int r = 0; r < 4; ++r) {
                const int row = row0 + i * 16 + r;
                float v = acc[i][j][r] + (BROW ? brow[i][r] : bv);
                if (EPI == 1) v = elu1(v);
                else if (EPI == 2) {
                    const bool kp = BROW ? ((row & 127) < 64) : kp_col;
                    if (kp) v = elu1(v);
                }
                store_out(C + (size_t)row * N + col, v);
            }
        }
    }
}

// ---------------------------------------------------------------------------
// OLD 128x128 ring GEMM (hardware-validated round 1) — kept for xd (N=256).
// ---------------------------------------------------------------------------
#define BM 128
#define BN 128
#define BK 32
#define NBUF 5

template<int EPI, bool BROW, typename OT>
__global__ __launch_bounds__(256) void gemm_bf16(
    const __hip_bfloat16* __restrict__ A,
    const __hip_bfloat16* __restrict__ Bt,
    const float* __restrict__ bias,
    OT* __restrict__ C,
    OT* __restrict__ C2,
    int M, int N, int K)
{
    __shared__ alignas(16) __hip_bfloat16 As[NBUF * BM * BK];
    __shared__ alignas(16) __hip_bfloat16 Bs[NBUF * BN * BK];

    const int nbx = N / BN;
    const int id = blockIdx.x;
    const int strip = id / (8 * nbx);
    const int wi = id % (8 * nbx);
    const int bm = (strip * 8 + (wi & 7)) * BM;
    const int bn = (wi >> 3) * BN;

    const int tid  = threadIdx.x;
    const int lane = tid & 63;
    const int wm   = (tid >> 7) * 64;
    const int wn   = ((tid >> 6) & 1) * 64;
    const int r15  = lane & 15;
    const int kg   = lane >> 4;

    f32x4 acc[4][4] = {};

    const int c0 = tid, c1 = tid + 256;
    const __hip_bfloat16* a0 = A  + (size_t)(bm + (c0 >> 2)) * K + (c0 & 3) * 8;
    const __hip_bfloat16* a1 = A  + (size_t)(bm + (c1 >> 2)) * K + (c1 & 3) * 8;
    const __hip_bfloat16* b0 = Bt + (size_t)(bn + (c0 >> 2)) * K + (c0 & 3) * 8;
    const __hip_bfloat16* b1 = Bt + (size_t)(bn + (c1 >> 2)) * K + (c1 & 3) * 8;

    const int nk = K / BK;

    auto stage = [&](int t) {
        const int buf = t % NBUF;
        __hip_bfloat16* Ad = As + buf * (BM * BK);
        __hip_bfloat16* Bd = Bs + buf * (BN * BK);
        const int k0 = t * BK;
        gld_lds16(a0 + k0, Ad + c0 * 8);
        gld_lds16(a1 + k0, Ad + c1 * 8);
        gld_lds16(b0 + k0, Bd + c0 * 8);
        gld_lds16(b1 + k0, Bd + c1 * 8);
    };

    stage(0); stage(1); stage(2);

    for (int t = 0; t < nk; ++t) {
        if (t + 3 < nk) {
            stage(t + 3);
            asm volatile("s_waitcnt vmcnt(12)\ns_barrier" ::: "memory");
        } else if (t + 2 < nk) {
            asm volatile("s_waitcnt vmcnt(8)\ns_barrier" ::: "memory");
        } else if (t + 1 < nk) {
            asm volatile("s_waitcnt vmcnt(4)\ns_barrier" ::: "memory");
        } else {
            asm volatile("s_waitcnt vmcnt(0)\ns_barrier" ::: "memory");
        }

        const __hip_bfloat16* Asb = As + (t % NBUF) * (BM * BK);
        const __hip_bfloat16* Bsb = Bs + (t % NBUF) * (BN * BK);

        short8 af[4], bf[4];
#pragma unroll
        for (int i = 0; i < 4; ++i) {
            af[i] = *(const short8*)(Asb + (wm + i * 16 + r15) * BK + kg * 8);
            bf[i] = *(const short8*)(Bsb + (wn + i * 16 + r15) * BK + kg * 8);
        }
#pragma unroll
        for (int i = 0; i < 4; ++i)
#pragma unroll
            for (int j = 0; j < 4; ++j)
                acc[i][j] = __builtin_amdgcn_mfma_f32_16x16x32_bf16(af[i], bf[j], acc[i][j], 0, 0, 0);
    }

    const int row0 = bm + wm + (lane >> 4) * 4;

    if (EPI == 3) {
        const bool qreg = (bn < 1024);
#pragma unroll
        for (int j = 0; j < 4; ++j) {
            const int col = bn + wn + j * 16 + r15;
            const float bv = bias[col];
#pragma unroll
            for (int i = 0; i < 4; ++i)
#pragma unroll
                for (int r = 0; r < 4; ++r) {
                    const int row = row0 + i * 16 + r;
                    float v = acc[i][j][r] + bv;
                    if (qreg) {
                        store_out(C + (size_t)row * 1024 + col, elu1(v));
                    } else {
                        store_out(C2 + (size_t)row * 256 + (col - 1024), v);
                    }
                }
        }
        return;
    }

    float brow[4][4];
    if (BROW) {
#pragma unroll
        for (int i = 0; i < 4; ++i)
#pragma unroll
            for (int r = 0; r < 4; ++r) brow[i][r] = bias[row0 + i * 16 + r];
    }
#pragma unroll
    for (int j = 0; j < 4; ++j) {
        const int col = bn + wn + j * 16 + r15;
        const float bv = BROW ? 0.0f : bias[col];
        const bool kp_col = ((col & 127) < 64);
#pragma unroll
        for (int i = 0; i < 4; ++i) {
#pragma unroll
            for (int r = 0; r < 4; ++r) {
                const int row = row0 + i * 16 + r;
                float v = acc[i][j][r] + (BROW ? brow[i][r] : bv);
                if (EPI == 1) v = elu1(v);
                else if (EPI == 2) {
                    const bool kp = BROW ? ((row & 127) < 64) : kp_col;
                    if (kp) v = elu1(v);
                }
                store_out(C + (size_t)row * N + col, v);
            }
        }
    }
}

// ---------------------------------------------------------------------------
__global__ __launch_bounds__(256) void cast_bf16_kernel(
    const float* __restrict__ s, __hip_bfloat16* __restrict__ d, int n)
{
    const int i = (blockIdx.x * 256 + threadIdx.x) * 8;
    if (i >= n) return;
    float4 v0 = *(const float4*)(s + i);
    float4 v1 = *(const float4*)(s + i + 4);
    __hip_bfloat16 t[8];
    t[0] = __float2bfloat16(v0.x); t[1] = __float2bfloat16(v0.y);
    t[2] = __float2bfloat16(v0.z); t[3] = __float2bfloat16(v0.w);
    t[4] = __float2bfloat16(v1.x); t[5] = __float2bfloat16(v1.y);
    t[6] = __float2bfloat16(v1.z); t[7] = __float2bfloat16(v1.w);
    *(short8*)(d + i) = *(const short8*)t;
}

__global__ __launch_bounds__(256) void transpose_cast(
    const float* __restrict__ W, __hip_bfloat16* __restrict__ Wt, int K, int N)
{
    __shared__ float t[32][33];
    const int n0 = blockIdx.x * 32, k0 = blockIdx.y * 32;
    const int c = threadIdx.x & 31, r = threadIdx.x >> 5;
#pragma unroll
    for (int rr = r; rr < 32; rr += 8)
        t[rr][c] = W[(size_t)(k0 + rr) * N + n0 + c];
    __syncthreads();
#pragma unroll
    for (int rr = r; rr < 32; rr += 8)
        Wt[(size_t)(n0 + rr) * K + k0 + c] = __float2bfloat16(t[c][rr]);
}

// ---------------------------------------------------------------------------
// ctx_mfma: ctx[bh][d][e] = sum_t K^T[d][t] * V^T[e][t]; ksum via ones-trick.
// ---------------------------------------------------------------------------
#define CHT 512

__global__ __launch_bounds__(256) void ctx_mfma(
    const __hip_bfloat16* __restrict__ kvT, float* __restrict__ ctx,
    float* __restrict__ ksum)
{
    __shared__ alignas(16) unsigned char smem[40960];
    float* red0 = (float*)smem;
    float* red1 = (float*)(smem + 20480);

    const int bh = blockIdx.x >> 3;
    const int chunk = blockIdx.x & 7;
    const int b = bh >> 4;
    const int h = bh & 15;
    const int tid = threadIdx.x;
    const int lane = tid & 63;
    const int w = tid >> 6;
    const int r15 = lane & 15;
    const int kg  = lane >> 4;

    f32x4 acc[4][4] = {};
    f32x4 acc4[4] = {};

    const short one = (short)0x3F80;
    const short8 bfv = (r15 == 0)
        ? (short8){one, one, one, one, one, one, one, one}
        : (short8){0, 0, 0, 0, 0, 0, 0, 0};

    const size_t tbase = (size_t)b * T_ + (size_t)chunk * CHT;
    const __hip_bfloat16* src = kvT + (size_t)(h * 128) * BT_ + tbase;

    for (int it = 0; it < CHT / 128; ++it) {
#pragma unroll
        for (int r = 0; r < 8; ++r) {
            const int c = r * 256 + tid;
            const int s = c >> 9, j = (c >> 2) & 127, u = c & 3;
            gld_lds16(src + (size_t)j * BT_ + it * 128 + s * 32 + u * 8,
                      smem + c * 16);
        }
        __syncthreads();

        const __hip_bfloat16* Ls = (const __hip_bfloat16*)smem;
        short8 af[4], bf[4];
#pragma unroll
        for (int i = 0; i < 4; ++i) {
            af[i] = *(const short8*)(Ls + (w * 128 + i * 16 + r15) * 32 + kg * 8);
            bf[i] = *(const short8*)(Ls + (w * 128 + 64 + i * 16 + r15) * 32 + kg * 8);
        }
#pragma unroll
        for (int i = 0; i < 4; ++i) {
#pragma unroll
            for (int j = 0; j < 4; ++j)
                acc[i][j] = __builtin_amdgcn_mfma_f32_16x16x32_bf16(af[i], bf[j], acc[i][j], 0, 0, 0);
            acc4[i] = __builtin_amdgcn_mfma_f32_16x16x32_bf16(af[i], bfv, acc4[i], 0, 0, 0);
        }
        __syncthreads();
    }

    const int q4 = lane >> 4;
    auto wr = [&](float* reg) {
#pragma unroll
        for (int i = 0; i < 4; ++i) {
#pragma unroll
            for (int r = 0; r < 4; ++r) {
                const int row = i * 16 + q4 * 4 + r;
#pragma unroll
                for (int j = 0; j < 4; ++j) reg[row * 80 + j * 16 + r15] = acc[i][j][r];
                reg[row * 80 + 64 + r15] = acc4[i][r];
            }
        }
    };
    auto rd = [&](const float* reg) {
#pragma unroll
        for (int i = 0; i < 4; ++i) {
#pragma unroll
            for (int r = 0; r < 4; ++r) {
                const int row = i * 16 + q4 * 4 + r;
#pragma unroll
                for (int j = 0; j < 4; ++j) acc[i][j][r] += reg[row * 80 + j * 16 + r15];
                acc4[i][r] += reg[row * 80 + 64 + r15];
            }
        }
    };

    if (w == 1) wr(red0);
    if (w == 3) wr(red1);
    __syncthreads();
    if (w == 0) rd(red0);
    if (w == 2) rd(red1);
    __syncthreads();
    if (w == 2) wr(red0);
    __syncthreads();
    if (w == 0) { rd(red0); wr(red0); }
    __syncthreads();

    float* cdst = ctx + (size_t)bh * 4096;
#pragma unroll
    for (int r = 0; r < 16; ++r) {
        const int idx = r * 256 + tid;
        const int d = idx >> 6, e = idx & 63;
        atomicAdd(cdst + idx, red0[d * 80 + e]);
    }
    if (tid < 64) atomicAdd(ksum + bh * 64 + tid, red0[tid * 80 + 64]);
}

// ---------------------------------------------------------------------------
__global__ __launch_bounds__(256) void pack_ctx(
    const float* __restrict__ ctx, __hip_bfloat16* __restrict__ ctxT)
{
    __shared__ float L[64 * 65];
    const int bh = blockIdx.x;
    const int tid = threadIdx.x;
#pragma unroll
    for (int r = 0; r < 16; ++r) {
        const int idx = r * 256 + tid;
        L[(idx >> 6) * 65 + (idx & 63)] = ctx[(size_t)bh * 4096 + idx];
    }
    __syncthreads();
#pragma unroll
    for (int r = 0; r < 16; ++r) {
        const int idx = r * 256 + tid;
        ctxT[(size_t)bh * 4096 + idx] =
            __float2bfloat16(L[(idx & 63) * 65 + (idx >> 6)]);
    }
}

// ---------------------------------------------------------------------------
// out_mfma: out[t][h*64+e] = z_t * sum_d q[t][d] * ctx[d][e]
// ---------------------------------------------------------------------------
__global__ __launch_bounds__(256) void out_mfma(
    const __hip_bfloat16* __restrict__ qb, const __hip_bfloat16* __restrict__ ctxT,
    const float* __restrict__ ksum, __hip_bfloat16* __restrict__ outb)
{
    __shared__ alignas(16) unsigned char As[256 * 128];
    __shared__ alignas(16) unsigned char Bs[64 * 128];
    __shared__ float ksumL[64];
    __shared__ float zbuf[256];

    const int bh = blockIdx.x >> 4;
    const int tile = blockIdx.x & 15;
    const int b = bh >> 4;
    const int h = bh & 15;
    const int tid = threadIdx.x;
    const int lane = tid & 63;
    const int w = tid >> 6;
    const int r15 = lane & 15;
    const int kg  = lane >> 4;

    const size_t trow0 = (size_t)b * T_ + (size_t)tile * 256;

#pragma unroll
    for (int r = 0; r < 8; ++r) {
        const int c = r * 256 + tid;
        const int row = c >> 3, slot = c & 7, u = slot ^ (row & 7);
        gld_lds16(qb + (trow0 + row) * D_ + h * 64 + u * 8, As + c * 16);
    }
#pragma unroll
    for (int r = 0; r < 2; ++r) {
        const int c = r * 256 + tid;
        const int row = c >> 3, slot = c & 7, u = slot ^ (row & 7);
        gld_lds16(ctxT + (size_t)bh * 4096 + row * 64 + u * 8, Bs + c * 16);
    }
    if (tid < 64) ksumL[tid] = ksum[bh * 64 + tid];
    __syncthreads();

    short8 af[4][2], bf[4][2];
#pragma unroll
    for (int i = 0; i < 4; ++i)
#pragma unroll
        for (int s = 0; s < 2; ++s) {
            const int m = w * 64 + i * 16 + r15;
            const int n = i * 16 + r15;
            const int uk = s * 4 + kg;
            af[i][s] = *(const short8*)(As + m * 128 + ((uk ^ (m & 7)) * 16));
            bf[i][s] = *(const short8*)(Bs + n * 128 + ((uk ^ (n & 7)) * 16));
        }

    f32x4 acc[4][4] = {};
#pragma unroll
    for (int s = 0; s < 2; ++s)
#pragma unroll
        for (int i = 0; i < 4; ++i)
#pragma unroll
            for (int j = 0; j < 4; ++j)
                acc[i][j] = __builtin_amdgcn_mfma_f32_16x16x32_bf16(af[i][s], bf[j][s], acc[i][j], 0, 0, 0);

    float dsum[4];
#pragma unroll
    for (int i = 0; i < 4; ++i) {
        float s0 = 0.0f;
#pragma unroll
        for (int s = 0; s < 2; ++s)
#pragma unroll
            for (int j8 = 0; j8 < 8; ++j8)
                s0 += bf2f(af[i][s][j8]) * ksumL[s * 32 + kg * 8 + j8];
        s0 += __shfl_xor(s0, 16);
        s0 += __shfl_xor(s0, 32);
        dsum[i] = s0;
    }
    if (lane < 16) {
#pragma unroll
        for (int i = 0; i < 4; ++i)
            zbuf[w * 64 + i * 16 + lane] = 1.0f / (dsum[i] + 1e-6f);
    }
    __syncthreads();

    const int q4 = lane >> 4;
#pragma unroll
    for (int i = 0; i < 4; ++i) {
#pragma unroll
        for (int r = 0; r < 4; ++r) {
            const int m = w * 64 + i * 16 + q4 * 4 + r;
            const float z = zbuf[m];
#pragma unroll
            for (int j = 0; j < 4; ++j) {
                outb[(trow0 + m) * D_ + h * 64 + j * 16 + r15] =
                    __float2bfloat16(acc[i][j][r] * z);
            }
        }
    }
}

// ---------------------------------------------------------------------------
extern "C" void kernel_launch(void* const* d_in, const int* in_sizes, int n_in,
                              void* d_out, int out_size, void* d_ws, size_t ws_size,
                              hipStream_t stream) {
    const float* x  = (const float*)d_in[0];
    const float* Wq = (const float*)d_in[1];
    const float* bq = (const float*)d_in[2];
    const float* Wd = (const float*)d_in[3];
    const float* bd = (const float*)d_in[4];
    const float* Wu = (const float*)d_in[5];
    const float* bu = (const float*)d_in[6];
    const float* Wo = (const float*)d_in[7];
    const float* bo = (const float*)d_in[8];
    float* out = (float*)d_out;

    __hip_bfloat16* xb    = (__hip_bfloat16*)d_ws;            // BT*D
    __hip_bfloat16* WqdT  = xb    + (size_t)BT_ * D_;         // [1280][1024]
    __hip_bfloat16* WuT   = WqdT  + (size_t)1280 * D_;        // [2048][256]
    __hip_bfloat16* WoT   = WuT   + (size_t)TWO_D_ * R_;      // [1024][1024]
    __hip_bfloat16* xdb   = WoT   + (size_t)D_ * D_;          // BT*R
    __hip_bfloat16* kvT   = xdb   + (size_t)BT_ * R_;         // 2048*BT
    __hip_bfloat16* qb    = kvT   + (size_t)TWO_D_ * BT_;     // BT*D
    float* bias_qd = (float*)(qb + (size_t)BT_ * D_);         // 1280 (unused now)
    float* ctx  = bias_qd + 1280;                             // 64*4096
    float* ksum = ctx + (size_t)B_ * H_ * DH_ * DH_;          // 64*64
    __hip_bfloat16* ctxT = (__hip_bfloat16*)(ksum + B_ * H_ * DH_);  // 64*4096
    __hip_bfloat16* outb = xb;   // alias: xb dead after q/xd GEMMs

    hipMemsetAsync(ctx, 0,
        (size_t)(B_ * H_ * DH_ * DH_ + B_ * H_ * DH_) * sizeof(float), stream);

    cast_bf16_kernel<<<(BT_ * D_) / (8 * 256), 256, 0, stream>>>(x, xb, BT_ * D_);
    transpose_cast<<<dim3(D_ / 32, D_ / 32), 256, 0, stream>>>(Wq, WqdT, D_, D_);
    transpose_cast<<<dim3(R_ / 32, D_ / 32), 256, 0, stream>>>(Wd, WqdT + (size_t)D_ * D_, D_, R_);
    transpose_cast<<<dim3(TWO_D_ / 32, R_ / 32), 256, 0, stream>>>(Wu, WuT, R_, TWO_D_);
    transpose_cast<<<dim3(D_ / 32, D_ / 32), 256, 0, stream>>>(Wo, WoT, D_, D_);

    // 1) xd = x @ Wd + bd    (old 128^2 ring; grid 256 = 1 block/CU)
    gemm_bf16<0, false, __hip_bfloat16><<<(BT_ / BM) * (R_ / BN), 256, 0, stream>>>(
        xb, WqdT + (size_t)D_ * D_, bd, xdb, nullptr, BT_, R_, D_);
    // 2) q = elu1(x @ Wq + bq)   (256^2 phased v3; grid 256 = 1 block/CU)
    gemm_p2<1, false, __hip_bfloat16><<<(BT_ / PBM) * (D_ / PBN), 512, 0, stream>>>(
        xb, WqdT, bq, qb, BT_, D_, D_);
    // 3) kvT[j][t] = Wu^T @ xd^T + bu[j], elu1 on rows (j&127)<64  (grid 512)
    gemm_p2<2, true, __hip_bfloat16><<<(TWO_D_ / PBM) * (BT_ / PBN), 512, 0, stream>>>(
        WuT, xdb, bu, kvT, TWO_D_, BT_, R_);
    // 4) ctx + ksum via MFMA
    ctx_mfma<<<64 * (T_ / CHT), 256, 0, stream>>>(kvT, ctx, ksum);
    // 5) pack ctx -> bf16 transposed
    pack_ctx<<<64, 256, 0, stream>>>(ctx, ctxT);
    // 6) out = z * (q @ ctx)
    out_mfma<<<64 * 16, 256, 0, stream>>>(qb, ctxT, ksum, outb);
    // 7) final = outb @ Wo + bo   (256^2 phased v3; grid 256)
    gemm_p2<0, false, float><<<(BT_ / PBM) * (D_ / PBN), 512, 0, stream>>>(
        outb, WoT, bo, out, BT_, D_, D_);
}

// Round 6
// 326.461 us; speedup vs baseline: 1.0296x; 1.0200x over previous
//
#include <hip/hip_runtime.h>
#include <hip/hip_bf16.h>
#include <cstddef>
#include <cstdint>

// Problem constants
#define B_  4
#define T_  4096
#define D_  1024
#define H_  16
#define DH_ 64
#define R_  256
#define BT_ (B_ * T_)       // 16384
#define TWO_D_ (2 * D_)     // 2048

typedef __attribute__((ext_vector_type(8))) short short8;
typedef __attribute__((ext_vector_type(4))) float f32x4;

__device__ __forceinline__ float elu1(float x) {
    return x > 0.0f ? x + 1.0f : __expf(x);
}

__device__ __forceinline__ float bf2f(short u) {
    union { uint32_t i; float f; } c;
    c.i = ((uint32_t)(uint16_t)u) << 16;
    return c.f;
}

typedef __attribute__((address_space(1))) void void_g;
typedef __attribute__((address_space(3))) void void_l;
__device__ __forceinline__ void gld_lds16(const void* g, void* l) {
    __builtin_amdgcn_global_load_lds(
        (const void_g*)(uintptr_t)g,
        (void_l*)(uint32_t)(uintptr_t)l,
        16, 0, 0);
}

__device__ __forceinline__ void store_out(float* p, float v) { *p = v; }
__device__ __forceinline__ void store_out(__hip_bfloat16* p, float v) { *p = __float2bfloat16(v); }

// ---------------------------------------------------------------------------
// 256x256 8-PHASE GEMM (m201-class: T2+T3+T4+T5).  C = A[M,K] @ Bt[N,K]^T + b.
// 512 thr = 8 waves (2M x 4N), per-wave 128x64.  BK=64, 2 K-tiles per
// iteration, double-buffered (buf = tile&1).  LDS: per matrix 4 half-buffers
// [buf][half] of 128 rows x 64 k = 16 KiB -> 128 KiB total.
// Per phase: {ds_reads for THIS phase's MFMA} {stage 1 half-tile (2 DMA)}
//            BARRIER; lgkm(0)+sched_barrier; setprio(1); 16 MFMA; setprio(0);
//            BARRIER.   vmcnt(4) ONLY at phases 4 and 8 (before mid-barrier).
// Quadrant walk (tile t):  ph1: i0-3 x j0-1 (reads af03+bf01 = 12)
//   ph2: i4-7 x j0-1 (reads af47 = 8);  ph3: i4-7 x j2-3 (reads bf23 = 4);
//   ph4: i0-3 x j2-3 (0 reads).  ph5-8 mirror for tile t+1.
// Stage slots: ph1 B(t+1)h0, ph2 B(t+1)h1, ph3 A(t+2)h0, ph4 A(t+2)h1,
//   ph5 B(t+2)h0, ph6 B(t+2)h1, ph7 A(t+3)h0, ph8 A(t+3)h1.
// WAR: each stage is >=1 collective barrier after its region's last read's
//   lgkm(0) drain (A(t) read ph1,ph2 -> stage ph3+; B(t) read ph1,ph3 ->
//   stage ph5+; A(t+1) read ph5,ph6 -> ph7+; B(t-1) read prev ph5,ph7 -> ph1).
// RAW: vmcnt(4) at ph4 leaves only ph3,ph4 stages in flight -> tile t+1
//   (A: prev ph7,8; B: ph1,2) confirmed by EVERY wave before the ph4 barrier;
//   ph5's reads follow that barrier (cross-wave safe).  ph8 likewise covers
//   tile t+2 for next ph1.  Prologue: 6 half-tiles, vmcnt(4), barrier.
// Tail: stage tile index clamped to nt-1 -> writes land in dead regions or
//   rewrite identical bytes; vmcnt counts stay uniform.
// LDS swizzle (G4, 128B rows): elem k' = k ^ ((row&7)<<3) on ds_read; the
//   staging SOURCE is pre-permuted with the same involution (rule #21):
//   chunk c -> row c>>3, slot c&7 holds k-group (c&7)^(row&7).
// ---------------------------------------------------------------------------
#define PBM 256
#define PBN 256

template<int EPI, bool BROW, typename OT>
__global__ __launch_bounds__(512, 2) void gemm_p8(
    const __hip_bfloat16* __restrict__ A,
    const __hip_bfloat16* __restrict__ Bt,
    const float* __restrict__ bias,
    OT* __restrict__ C,
    int M, int N, int K)
{
    __shared__ alignas(16) __hip_bfloat16 sm[65536];  // 128 KiB
    __hip_bfloat16* Asm = sm;            // 4 x 8192 (buf*2+half)
    __hip_bfloat16* Bsm = sm + 32768;

    // strip swizzle: strips of sh row-tiles, col-major within strip
    const int nbx = N / PBN;
    const int nbm = M / PBM;
    const int sh = (nbm < 8) ? nbm : 8;
    const int id = blockIdx.x;
    const int wi = id % (sh * nbx);
    const int bm = ((id / (sh * nbx)) * sh + (wi % sh)) * PBM;
    const int bn = (wi / sh) * PBN;

    const int tid  = threadIdx.x;
    const int lane = tid & 63;
    const int w    = tid >> 6;
    const int wm   = w >> 2;        // 0..1
    const int wn   = w & 3;         // 0..3
    const int r15  = lane & 15;
    const int kg   = lane >> 4;

    const int nt = K / 64;          // K-tiles; even, >= 4 at all call sites

    // ---- staging precompute: chunk c -> row c>>3, k-group (c&7)^(row&7) ----
    const int rl = tid >> 3;                 // rows 0..63 (c1: +64)
    const int g  = (tid & 7) ^ (rl & 7);     // same for c1 (+64 = 0 mod 8)
    const __hip_bfloat16* aS = A  + (size_t)(bm + rl) * K + g * 8;
    const __hip_bfloat16* bS = Bt + (size_t)(bn + rl) * K + g * 8;
    __hip_bfloat16* dA = Asm + tid * 8;
    __hip_bfloat16* dB = Bsm + tid * 8;

    auto stA = [&](int t, int h) {
        const int tc = (t < nt) ? t : (nt - 1);      // tail clamp
        __hip_bfloat16* d = dA + ((t & 1) * 2 + h) * 8192;
        const __hip_bfloat16* s = aS + (size_t)(h * 128) * K + tc * 64;
        gld_lds16(s, d);
        gld_lds16(s + (size_t)64 * K, d + 4096);
    };
    auto stB = [&](int t, int h) {
        const int tc = (t < nt) ? t : (nt - 1);
        __hip_bfloat16* d = dB + ((t & 1) * 2 + h) * 8192;
        const __hip_bfloat16* s = bS + (size_t)(h * 128) * K + tc * 64;
        gld_lds16(s, d);
        gld_lds16(s + (size_t)64 * K, d + 4096);
    };

    // ---- fragment read bases (swizzled) ----
    const int x3    = (r15 & 7) << 3;
    const int kofs0 = (kg * 8) ^ x3;          // ksl 0
    const int kofs1 = (32 + kg * 8) ^ x3;     // ksl 1
    const __hip_bfloat16* Af0 = Asm + wm * 8192 + r15 * 64;                    // buf0
    const __hip_bfloat16* Bf0 = Bsm + (wn >> 1) * 8192 + (wn & 1) * 4096 + r15 * 64;
    const __hip_bfloat16* Af1 = Af0 + 16384;                                   // buf1
    const __hip_bfloat16* Bf1 = Bf0 + 16384;

    f32x4 acc[8][4] = {};
    short8 af[8][2], bf[4][2];

    // ---- prologue: A(0), B(0), A(1); confirm tile 0; collective ----
    stA(0, 0); stA(0, 1); stB(0, 0); stB(0, 1); stA(1, 0); stA(1, 1);
    asm volatile("s_waitcnt vmcnt(4)" ::: "memory");
    __builtin_amdgcn_s_barrier();

    for (int t = 0; t < nt; t += 2) {
        // ================= tile t (buf0) =================
        // ---- ph1: reads af03+bf01 | stage B(t+1)h0 | MFMA i0-3 x j0-1 ----
#pragma unroll
        for (int i = 0; i < 4; ++i) {
            af[i][0] = *(const short8*)(Af0 + i * 1024 + kofs0);
            af[i][1] = *(const short8*)(Af0 + i * 1024 + kofs1);
        }
#pragma unroll
        for (int j = 0; j < 2; ++j) {
            bf[j][0] = *(const short8*)(Bf0 + j * 1024 + kofs0);
            bf[j][1] = *(const short8*)(Bf0 + j * 1024 + kofs1);
        }
        stB(t + 1, 0);
        __builtin_amdgcn_s_barrier();
        asm volatile("s_waitcnt lgkmcnt(0)" ::: "memory");
        __builtin_amdgcn_sched_barrier(0);
        __builtin_amdgcn_s_setprio(1);
#pragma unroll
        for (int i = 0; i < 4; ++i)
#pragma unroll
            for (int j = 0; j < 2; ++j) {
                acc[i][j] = __builtin_amdgcn_mfma_f32_16x16x32_bf16(af[i][0], bf[j][0], acc[i][j], 0, 0, 0);
                acc[i][j] = __builtin_amdgcn_mfma_f32_16x16x32_bf16(af[i][1], bf[j][1], acc[i][j], 0, 0, 0);
            }
        __builtin_amdgcn_s_setprio(0);
        __builtin_amdgcn_s_barrier();

        // ---- ph2: reads af47 | stage B(t+1)h1 | MFMA i4-7 x j0-1 ----
#pragma unroll
        for (int i = 4; i < 8; ++i) {
            af[i][0] = *(const short8*)(Af0 + i * 1024 + kofs0);
            af[i][1] = *(const short8*)(Af0 + i * 1024 + kofs1);
        }
        stB(t + 1, 1);
        __builtin_amdgcn_s_barrier();
        asm volatile("s_waitcnt lgkmcnt(0)" ::: "memory");
        __builtin_amdgcn_sched_barrier(0);
        __builtin_amdgcn_s_setprio(1);
#pragma unroll
        for (int i = 4; i < 8; ++i)
#pragma unroll
            for (int j = 0; j < 2; ++j) {
                acc[i][j] = __builtin_amdgcn_mfma_f32_16x16x32_bf16(af[i][0], bf[j][0], acc[i][j], 0, 0, 0);
                acc[i][j] = __builtin_amdgcn_mfma_f32_16x16x32_bf16(af[i][1], bf[j][1], acc[i][j], 0, 0, 0);
            }
        __builtin_amdgcn_s_setprio(0);
        __builtin_amdgcn_s_barrier();

        // ---- ph3: reads bf23 | stage A(t+2)h0 | MFMA i4-7 x j2-3 ----
#pragma unroll
        for (int j = 2; j < 4; ++j) {
            bf[j][0] = *(const short8*)(Bf0 + j * 1024 + kofs0);
            bf[j][1] = *(const short8*)(Bf0 + j * 1024 + kofs1);
        }
        stA(t + 2, 0);
        __builtin_amdgcn_s_barrier();
        asm volatile("s_waitcnt lgkmcnt(0)" ::: "memory");
        __builtin_amdgcn_sched_barrier(0);
        __builtin_amdgcn_s_setprio(1);
#pragma unroll
        for (int i = 4; i < 8; ++i)
#pragma unroll
            for (int j = 2; j < 4; ++j) {
                acc[i][j] = __builtin_amdgcn_mfma_f32_16x16x32_bf16(af[i][0], bf[j][0], acc[i][j], 0, 0, 0);
                acc[i][j] = __builtin_amdgcn_mfma_f32_16x16x32_bf16(af[i][1], bf[j][1], acc[i][j], 0, 0, 0);
            }
        __builtin_amdgcn_s_setprio(0);
        __builtin_amdgcn_s_barrier();

        // ---- ph4: stage A(t+2)h1 | vmcnt(4) | MFMA i0-3 x j2-3 ----
        stA(t + 2, 1);
        asm volatile("s_waitcnt vmcnt(4)" ::: "memory");
        __builtin_amdgcn_s_barrier();
        __builtin_amdgcn_sched_barrier(0);
        __builtin_amdgcn_s_setprio(1);
#pragma unroll
        for (int i = 0; i < 4; ++i)
#pragma unroll
            for (int j = 2; j < 4; ++j) {
                acc[i][j] = __builtin_amdgcn_mfma_f32_16x16x32_bf16(af[i][0], bf[j][0], acc[i][j], 0, 0, 0);
                acc[i][j] = __builtin_amdgcn_mfma_f32_16x16x32_bf16(af[i][1], bf[j][1], acc[i][j], 0, 0, 0);
            }
        __builtin_amdgcn_s_setprio(0);
        __builtin_amdgcn_s_barrier();

        // ================= tile t+1 (buf1) =================
        // ---- ph5: reads af03+bf01 | stage B(t+2)h0 | MFMA i0-3 x j0-1 ----
#pragma unroll
        for (int i = 0; i < 4; ++i) {
            af[i][0] = *(const short8*)(Af1 + i * 1024 + kofs0);
            af[i][1] = *(const short8*)(Af1 + i * 1024 + kofs1);
        }
#pragma unroll
        for (int j = 0; j < 2; ++j) {
            bf[j][0] = *(const short8*)(Bf1 + j * 1024 + kofs0);
            bf[j][1] = *(const short8*)(Bf1 + j * 1024 + kofs1);
        }
        stB(t + 2, 0);
        __builtin_amdgcn_s_barrier();
        asm volatile("s_waitcnt lgkmcnt(0)" ::: "memory");
        __builtin_amdgcn_sched_barrier(0);
        __builtin_amdgcn_s_setprio(1);
#pragma unroll
        for (int i = 0; i < 4; ++i)
#pragma unroll
            for (int j = 0; j < 2; ++j) {
                acc[i][j] = __builtin_amdgcn_mfma_f32_16x16x32_bf16(af[i][0], bf[j][0], acc[i][j], 0, 0, 0);
                acc[i][j] = __builtin_amdgcn_mfma_f32_16x16x32_bf16(af[i][1], bf[j][1], acc[i][j], 0, 0, 0);
            }
        __builtin_amdgcn_s_setprio(0);
        __builtin_amdgcn_s_barrier();

        // ---- ph6: reads af47 | stage B(t+2)h1 | MFMA i4-7 x j0-1 ----
#pragma unroll
        for (int i = 4; i < 8; ++i) {
            af[i][0] = *(const short8*)(Af1 + i * 1024 + kofs0);
            af[i][1] = *(const short8*)(Af1 + i * 1024 + kofs1);
        }
        stB(t + 2, 1);
        __builtin_amdgcn_s_barrier();
        asm volatile("s_waitcnt lgkmcnt(0)" ::: "memory");
        __builtin_amdgcn_sched_barrier(0);
        __builtin_amdgcn_s_setprio(1);
#pragma unroll
        for (int i = 4; i < 8; ++i)
#pragma unroll
            for (int j = 0; j < 2; ++j) {
                acc[i][j] = __builtin_amdgcn_mfma_f32_16x16x32_bf16(af[i][0], bf[j][0], acc[i][j], 0, 0, 0);
                acc[i][j] = __builtin_amdgcn_mfma_f32_16x16x32_bf16(af[i][1], bf[j][1], acc[i][j], 0, 0, 0);
            }
        __builtin_amdgcn_s_setprio(0);
        __builtin_amdgcn_s_barrier();

        // ---- ph7: reads bf23 | stage A(t+3)h0 | MFMA i4-7 x j2-3 ----
#pragma unroll
        for (int j = 2; j < 4; ++j) {
            bf[j][0] = *(const short8*)(Bf1 + j * 1024 + kofs0);
            bf[j][1] = *(const short8*)(Bf1 + j * 1024 + kofs1);
        }
        stA(t + 3, 0);
        __builtin_amdgcn_s_barrier();
        asm volatile("s_waitcnt lgkmcnt(0)" ::: "memory");
        __builtin_amdgcn_sched_barrier(0);
        __builtin_amdgcn_s_setprio(1);
#pragma unroll
        for (int i = 4; i < 8; ++i)
#pragma unroll
            for (int j = 2; j < 4; ++j) {
                acc[i][j] = __builtin_amdgcn_mfma_f32_16x16x32_bf16(af[i][0], bf[j][0], acc[i][j], 0, 0, 0);
                acc[i][j] = __builtin_amdgcn_mfma_f32_16x16x32_bf16(af[i][1], bf[j][1], acc[i][j], 0, 0, 0);
            }
        __builtin_amdgcn_s_setprio(0);
        __builtin_amdgcn_s_barrier();

        // ---- ph8: stage A(t+3)h1 | vmcnt(4) | MFMA i0-3 x j2-3 ----
        stA(t + 3, 1);
        asm volatile("s_waitcnt vmcnt(4)" ::: "memory");
        __builtin_amdgcn_s_barrier();
        __builtin_amdgcn_sched_barrier(0);
        __builtin_amdgcn_s_setprio(1);
#pragma unroll
        for (int i = 0; i < 4; ++i)
#pragma unroll
            for (int j = 2; j < 4; ++j) {
                acc[i][j] = __builtin_amdgcn_mfma_f32_16x16x32_bf16(af[i][0], bf[j][0], acc[i][j], 0, 0, 0);
                acc[i][j] = __builtin_amdgcn_mfma_f32_16x16x32_bf16(af[i][1], bf[j][1], acc[i][j], 0, 0, 0);
            }
        __builtin_amdgcn_s_setprio(0);
        __builtin_amdgcn_s_barrier();
    }
    asm volatile("s_waitcnt vmcnt(0)" ::: "memory");   // drain tail DMA

    // epilogue; C/D layout: col=lane&15, row=(lane>>4)*4+reg  [m89-verified]
    const int row0 = bm + wm * 128 + (lane >> 4) * 4;

    float brow[8][4];
    if (BROW) {
#pragma unroll
        for (int i = 0; i < 8; ++i)
#pragma unroll
            for (int r = 0; r < 4; ++r) brow[i][r] = bias[row0 + i * 16 + r];
    }
#pragma unroll
    for (int j = 0; j < 4; ++j) {
        const int col = bn + wn * 64 + j * 16 + r15;
        const float bv = BROW ? 0.0f : bias[col];
        const bool kp_col = ((col & 127) < 64);
#pragma unroll
        for (int i = 0; i < 8; ++i) {
#pragma unroll
            for (int r = 0; r < 4; ++r) {
                const int row = row0 + i * 16 + r;
                float v = acc[i][j][r] + (BROW ? brow[i][r] : bv);
                if (EPI == 1) v = elu1(v);
                else if (EPI == 2) {
                    const bool kp = BROW ? ((row & 127) < 64) : kp_col;
                    if (kp) v = elu1(v);
                }
                store_out(C + (size_t)row * N + col, v);
            }
        }
    }
}

// ---------------------------------------------------------------------------
// OLD 128x128 ring GEMM (hardware-validated round 1) — kept for xd (N=256).
// ---------------------------------------------------------------------------
#define BM 128
#define BN 128
#define BK 32
#define NBUF 5

template<int EPI, bool BROW, typename OT>
__global__ __launch_bounds__(256) void gemm_bf16(
    const __hip_bfloat16* __restrict__ A,
    const __hip_bfloat16* __restrict__ Bt,
    const float* __restrict__ bias,
    OT* __restrict__ C,
    OT* __restrict__ C2,
    int M, int N, int K)
{
    __shared__ alignas(16) __hip_bfloat16 As[NBUF * BM * BK];
    __shared__ alignas(16) __hip_bfloat16 Bs[NBUF * BN * BK];

    const int nbx = N / BN;
    const int id = blockIdx.x;
    const int strip = id / (8 * nbx);
    const int wi = id % (8 * nbx);
    const int bm = (strip * 8 + (wi & 7)) * BM;
    const int bn = (wi >> 3) * BN;

    const int tid  = threadIdx.x;
    const int lane = tid & 63;
    const int wm   = (tid >> 7) * 64;
    const int wn   = ((tid >> 6) & 1) * 64;
    const int r15  = lane & 15;
    const int kg   = lane >> 4;

    f32x4 acc[4][4] = {};

    const int c0 = tid, c1 = tid + 256;
    const __hip_bfloat16* a0 = A  + (size_t)(bm + (c0 >> 2)) * K + (c0 & 3) * 8;
    const __hip_bfloat16* a1 = A  + (size_t)(bm + (c1 >> 2)) * K + (c1 & 3) * 8;
    const __hip_bfloat16* b0 = Bt + (size_t)(bn + (c0 >> 2)) * K + (c0 & 3) * 8;
    const __hip_bfloat16* b1 = Bt + (size_t)(bn + (c1 >> 2)) * K + (c1 & 3) * 8;

    const int nk = K / BK;

    auto stage = [&](int t) {
        const int buf = t % NBUF;
        __hip_bfloat16* Ad = As + buf * (BM * BK);
        __hip_bfloat16* Bd = Bs + buf * (BN * BK);
        const int k0 = t * BK;
        gld_lds16(a0 + k0, Ad + c0 * 8);
        gld_lds16(a1 + k0, Ad + c1 * 8);
        gld_lds16(b0 + k0, Bd + c0 * 8);
        gld_lds16(b1 + k0, Bd + c1 * 8);
    };

    stage(0); stage(1); stage(2);

    for (int t = 0; t < nk; ++t) {
        if (t + 3 < nk) {
            stage(t + 3);
            asm volatile("s_waitcnt vmcnt(12)\ns_barrier" ::: "memory");
        } else if (t + 2 < nk) {
            asm volatile("s_waitcnt vmcnt(8)\ns_barrier" ::: "memory");
        } else if (t + 1 < nk) {
            asm volatile("s_waitcnt vmcnt(4)\ns_barrier" ::: "memory");
        } else {
            asm volatile("s_waitcnt vmcnt(0)\ns_barrier" ::: "memory");
        }

        const __hip_bfloat16* Asb = As + (t % NBUF) * (BM * BK);
        const __hip_bfloat16* Bsb = Bs + (t % NBUF) * (BN * BK);

        short8 af[4], bf[4];
#pragma unroll
        for (int i = 0; i < 4; ++i) {
            af[i] = *(const short8*)(Asb + (wm + i * 16 + r15) * BK + kg * 8);
            bf[i] = *(const short8*)(Bsb + (wn + i * 16 + r15) * BK + kg * 8);
        }
#pragma unroll
        for (int i = 0; i < 4; ++i)
#pragma unroll
            for (int j = 0; j < 4; ++j)
                acc[i][j] = __builtin_amdgcn_mfma_f32_16x16x32_bf16(af[i], bf[j], acc[i][j], 0, 0, 0);
    }

    const int row0 = bm + wm + (lane >> 4) * 4;

    if (EPI == 3) {
        const bool qreg = (bn < 1024);
#pragma unroll
        for (int j = 0; j < 4; ++j) {
            const int col = bn + wn + j * 16 + r15;
            const float bv = bias[col];
#pragma unroll
            for (int i = 0; i < 4; ++i)
#pragma unroll
                for (int r = 0; r < 4; ++r) {
                    const int row = row0 + i * 16 + r;
                    float v = acc[i][j][r] + bv;
                    if (qreg) {
                        store_out(C + (size_t)row * 1024 + col, elu1(v));
                    } else {
                        store_out(C2 + (size_t)row * 256 + (col - 1024), v);
                    }
                }
        }
        return;
    }

    float brow[4][4];
    if (BROW) {
#pragma unroll
        for (int i = 0; i < 4; ++i)
#pragma unroll
            for (int r = 0; r < 4; ++r) brow[i][r] = bias[row0 + i * 16 + r];
    }
#pragma unroll
    for (int j = 0; j < 4; ++j) {
        const int col = bn + wn + j * 16 + r15;
        const float bv = BROW ? 0.0f : bias[col];
        const bool kp_col = ((col & 127) < 64);
#pragma unroll
        for (int i = 0; i < 4; ++i) {
#pragma unroll
            for (int r = 0; r < 4; ++r) {
                const int row = row0 + i * 16 + r;
                float v = acc[i][j][r] + (BROW ? brow[i][r] : bv);
                if (EPI == 1) v = elu1(v);
                else if (EPI == 2) {
                    const bool kp = BROW ? ((row & 127) < 64) : kp_col;
                    if (kp) v = elu1(v);
                }
                store_out(C + (size_t)row * N + col, v);
            }
        }
    }
}

// ---------------------------------------------------------------------------
__global__ __launch_bounds__(256) void cast_bf16_kernel(
    const float* __restrict__ s, __hip_bfloat16* __restrict__ d, int n)
{
    const int i = (blockIdx.x * 256 + threadIdx.x) * 8;
    if (i >= n) return;
    float4 v0 = *(const float4*)(s + i);
    float4 v1 = *(const float4*)(s + i + 4);
    __hip_bfloat16 t[8];
    t[0] = __float2bfloat16(v0.x); t[1] = __float2bfloat16(v0.y);
    t[2] = __float2bfloat16(v0.z); t[3] = __float2bfloat16(v0.w);
    t[4] = __float2bfloat16(v1.x); t[5] = __float2bfloat16(v1.y);
    t[6] = __float2bfloat16(v1.z); t[7] = __float2bfloat16(v1.w);
    *(short8*)(d + i) = *(const short8*)t;
}

__global__ __launch_bounds__(256) void transpose_cast(
    const float* __restrict__ W, __hip_bfloat16* __restrict__ Wt, int K, int N)
{
    __shared__ float t[32][33];
    const int n0 = blockIdx.x * 32, k0 = blockIdx.y * 32;
    const int c = threadIdx.x & 31, r = threadIdx.x >> 5;
#pragma unroll
    for (int rr = r; rr < 32; rr += 8)
        t[rr][c] = W[(size_t)(k0 + rr) * N + n0 + c];
    __syncthreads();
#pragma unroll
    for (int rr = r; rr < 32; rr += 8)
        Wt[(size_t)(n0 + rr) * K + k0 + c] = __float2bfloat16(t[c][rr]);
}

// ---------------------------------------------------------------------------
// ctx_mfma: ctx[bh][d][e] = sum_t K^T[d][t] * V^T[e][t]; ksum via ones-trick.
// ---------------------------------------------------------------------------
#define CHT 512

__global__ __launch_bounds__(256) void ctx_mfma(
    const __hip_bfloat16* __restrict__ kvT, float* __restrict__ ctx,
    float* __restrict__ ksum)
{
    __shared__ alignas(16) unsigned char smem[40960];
    float* red0 = (float*)smem;
    float* red1 = (float*)(smem + 20480);

    const int bh = blockIdx.x >> 3;
    const int chunk = blockIdx.x & 7;
    const int b = bh >> 4;
    const int h = bh & 15;
    const int tid = threadIdx.x;
    const int lane = tid & 63;
    const int w = tid >> 6;
    const int r15 = lane & 15;
    const int kg  = lane >> 4;

    f32x4 acc[4][4] = {};
    f32x4 acc4[4] = {};

    const short one = (short)0x3F80;
    const short8 bfv = (r15 == 0)
        ? (short8){one, one, one, one, one, one, one, one}
        : (short8){0, 0, 0, 0, 0, 0, 0, 0};

    const size_t tbase = (size_t)b * T_ + (size_t)chunk * CHT;
    const __hip_bfloat16* src = kvT + (size_t)(h * 128) * BT_ + tbase;

    for (int it = 0; it < CHT / 128; ++it) {
#pragma unroll
        for (int r = 0; r < 8; ++r) {
            const int c = r * 256 + tid;
            const int s = c >> 9, j = (c >> 2) & 127, u = c & 3;
            gld_lds16(src + (size_t)j * BT_ + it * 128 + s * 32 + u * 8,
                      smem + c * 16);
        }
        __syncthreads();

        const __hip_bfloat16* Ls = (const __hip_bfloat16*)smem;
        short8 af[4], bf[4];
#pragma unroll
        for (int i = 0; i < 4; ++i) {
            af[i] = *(const short8*)(Ls + (w * 128 + i * 16 + r15) * 32 + kg * 8);
            bf[i] = *(const short8*)(Ls + (w * 128 + 64 + i * 16 + r15) * 32 + kg * 8);
        }
#pragma unroll
        for (int i = 0; i < 4; ++i) {
#pragma unroll
            for (int j = 0; j < 4; ++j)
                acc[i][j] = __builtin_amdgcn_mfma_f32_16x16x32_bf16(af[i], bf[j], acc[i][j], 0, 0, 0);
            acc4[i] = __builtin_amdgcn_mfma_f32_16x16x32_bf16(af[i], bfv, acc4[i], 0, 0, 0);
        }
        __syncthreads();
    }

    const int q4 = lane >> 4;
    auto wr = [&](float* reg) {
#pragma unroll
        for (int i = 0; i < 4; ++i) {
#pragma unroll
            for (int r = 0; r < 4; ++r) {
                const int row = i * 16 + q4 * 4 + r;
#pragma unroll
                for (int j = 0; j < 4; ++j) reg[row * 80 + j * 16 + r15] = acc[i][j][r];
                reg[row * 80 + 64 + r15] = acc4[i][r];
            }
        }
    };
    auto rd = [&](const float* reg) {
#pragma unroll
        for (int i = 0; i < 4; ++i) {
#pragma unroll
            for (int r = 0; r < 4; ++r) {
                const int row = i * 16 + q4 * 4 + r;
#pragma unroll
                for (int j = 0; j < 4; ++j) acc[i][j][r] += reg[row * 80 + j * 16 + r15];
                acc4[i][r] += reg[row * 80 + 64 + r15];
            }
        }
    };

    if (w == 1) wr(red0);
    if (w == 3) wr(red1);
    __syncthreads();
    if (w == 0) rd(red0);
    if (w == 2) rd(red1);
    __syncthreads();
    if (w == 2) wr(red0);
    __syncthreads();
    if (w == 0) { rd(red0); wr(red0); }
    __syncthreads();

    float* cdst = ctx + (size_t)bh * 4096;
#pragma unroll
    for (int r = 0; r < 16; ++r) {
        const int idx = r * 256 + tid;
        const int d = idx >> 6, e = idx & 63;
        atomicAdd(cdst + idx, red0[d * 80 + e]);
    }
    if (tid < 64) atomicAdd(ksum + bh * 64 + tid, red0[tid * 80 + 64]);
}

// ---------------------------------------------------------------------------
__global__ __launch_bounds__(256) void pack_ctx(
    const float* __restrict__ ctx, __hip_bfloat16* __restrict__ ctxT)
{
    __shared__ float L[64 * 65];
    const int bh = blockIdx.x;
    const int tid = threadIdx.x;
#pragma unroll
    for (int r = 0; r < 16; ++r) {
        const int idx = r * 256 + tid;
        L[(idx >> 6) * 65 + (idx & 63)] = ctx[(size_t)bh * 4096 + idx];
    }
    __syncthreads();
#pragma unroll
    for (int r = 0; r < 16; ++r) {
        const int idx = r * 256 + tid;
        ctxT[(size_t)bh * 4096 + idx] =
            __float2bfloat16(L[(idx & 63) * 65 + (idx >> 6)]);
    }
}

// ---------------------------------------------------------------------------
// out_mfma: out[t][h*64+e] = z_t * sum_d q[t][d] * ctx[d][e]
// ---------------------------------------------------------------------------
__global__ __launch_bounds__(256) void out_mfma(
    const __hip_bfloat16* __restrict__ qb, const __hip_bfloat16* __restrict__ ctxT,
    const float* __restrict__ ksum, __hip_bfloat16* __restrict__ outb)
{
    __shared__ alignas(16) unsigned char As[256 * 128];
    __shared__ alignas(16) unsigned char Bs[64 * 128];
    __shared__ float ksumL[64];
    __shared__ float zbuf[256];

    const int bh = blockIdx.x >> 4;
    const int tile = blockIdx.x & 15;
    const int b = bh >> 4;
    const int h = bh & 15;
    const int tid = threadIdx.x;
    const int lane = tid & 63;
    const int w = tid >> 6;
    const int r15 = lane & 15;
    const int kg  = lane >> 4;

    const size_t trow0 = (size_t)b * T_ + (size_t)tile * 256;

#pragma unroll
    for (int r = 0; r < 8; ++r) {
        const int c = r * 256 + tid;
        const int row = c >> 3, slot = c & 7, u = slot ^ (row & 7);
        gld_lds16(qb + (trow0 + row) * D_ + h * 64 + u * 8, As + c * 16);
    }
#pragma unroll
    for (int r = 0; r < 2; ++r) {
        const int c = r * 256 + tid;
        const int row = c >> 3, slot = c & 7, u = slot ^ (row & 7);
        gld_lds16(ctxT + (size_t)bh * 4096 + row * 64 + u * 8, Bs + c * 16);
    }
    if (tid < 64) ksumL[tid] = ksum[bh * 64 + tid];
    __syncthreads();

    short8 af[4][2], bf[4][2];
#pragma unroll
    for (int i = 0; i < 4; ++i)
#pragma unroll
        for (int s = 0; s < 2; ++s) {
            const int m = w * 64 + i * 16 + r15;
            const int n = i * 16 + r15;
            const int uk = s * 4 + kg;
            af[i][s] = *(const short8*)(As + m * 128 + ((uk ^ (m & 7)) * 16));
            bf[i][s] = *(const short8*)(Bs + n * 128 + ((uk ^ (n & 7)) * 16));
        }

    f32x4 acc[4][4] = {};
#pragma unroll
    for (int s = 0; s < 2; ++s)
#pragma unroll
        for (int i = 0; i < 4; ++i)
#pragma unroll
            for (int j = 0; j < 4; ++j)
                acc[i][j] = __builtin_amdgcn_mfma_f32_16x16x32_bf16(af[i][s], bf[j][s], acc[i][j], 0, 0, 0);

    float dsum[4];
#pragma unroll
    for (int i = 0; i < 4; ++i) {
        float s0 = 0.0f;
#pragma unroll
        for (int s = 0; s < 2; ++s)
#pragma unroll
            for (int j8 = 0; j8 < 8; ++j8)
                s0 += bf2f(af[i][s][j8]) * ksumL[s * 32 + kg * 8 + j8];
        s0 += __shfl_xor(s0, 16);
        s0 += __shfl_xor(s0, 32);
        dsum[i] = s0;
    }
    if (lane < 16) {
#pragma unroll
        for (int i = 0; i < 4; ++i)
            zbuf[w * 64 + i * 16 + lane] = 1.0f / (dsum[i] + 1e-6f);
    }
    __syncthreads();

    const int q4 = lane >> 4;
#pragma unroll
    for (int i = 0; i < 4; ++i) {
#pragma unroll
        for (int r = 0; r < 4; ++r) {
            const int m = w * 64 + i * 16 + q4 * 4 + r;
            const float z = zbuf[m];
#pragma unroll
            for (int j = 0; j < 4; ++j) {
                outb[(trow0 + m) * D_ + h * 64 + j * 16 + r15] =
                    __float2bfloat16(acc[i][j][r] * z);
            }
        }
    }
}

// ---------------------------------------------------------------------------
extern "C" void kernel_launch(void* const* d_in, const int* in_sizes, int n_in,
                              void* d_out, int out_size, void* d_ws, size_t ws_size,
                              hipStream_t stream) {
    const float* x  = (const float*)d_in[0];
    const float* Wq = (const float*)d_in[1];
    const float* bq = (const float*)d_in[2];
    const float* Wd = (const float*)d_in[3];
    const float* bd = (const float*)d_in[4];
    const float* Wu = (const float*)d_in[5];
    const float* bu = (const float*)d_in[6];
    const float* Wo = (const float*)d_in[7];
    const float* bo = (const float*)d_in[8];
    float* out = (float*)d_out;

    __hip_bfloat16* xb    = (__hip_bfloat16*)d_ws;            // BT*D
    __hip_bfloat16* WqdT  = xb    + (size_t)BT_ * D_;         // [1280][1024]
    __hip_bfloat16* WuT   = WqdT  + (size_t)1280 * D_;        // [2048][256]
    __hip_bfloat16* WoT   = WuT   + (size_t)TWO_D_ * R_;      // [1024][1024]
    __hip_bfloat16* xdb   = WoT   + (size_t)D_ * D_;          // BT*R
    __hip_bfloat16* kvT   = xdb   + (size_t)BT_ * R_;         // 2048*BT
    __hip_bfloat16* qb    = kvT   + (size_t)TWO_D_ * BT_;     // BT*D
    float* bias_qd = (float*)(qb + (size_t)BT_ * D_);         // 1280 (unused now)
    float* ctx  = bias_qd + 1280;                             // 64*4096
    float* ksum = ctx + (size_t)B_ * H_ * DH_ * DH_;          // 64*64
    __hip_bfloat16* ctxT = (__hip_bfloat16*)(ksum + B_ * H_ * DH_);  // 64*4096
    __hip_bfloat16* outb = xb;   // alias: xb dead after q/xd GEMMs

    hipMemsetAsync(ctx, 0,
        (size_t)(B_ * H_ * DH_ * DH_ + B_ * H_ * DH_) * sizeof(float), stream);

    cast_bf16_kernel<<<(BT_ * D_) / (8 * 256), 256, 0, stream>>>(x, xb, BT_ * D_);
    transpose_cast<<<dim3(D_ / 32, D_ / 32), 256, 0, stream>>>(Wq, WqdT, D_, D_);
    transpose_cast<<<dim3(R_ / 32, D_ / 32), 256, 0, stream>>>(Wd, WqdT + (size_t)D_ * D_, D_, R_);
    transpose_cast<<<dim3(TWO_D_ / 32, R_ / 32), 256, 0, stream>>>(Wu, WuT, R_, TWO_D_);
    transpose_cast<<<dim3(D_ / 32, D_ / 32), 256, 0, stream>>>(Wo, WoT, D_, D_);

    // 1) xd = x @ Wd + bd    (128^2 ring; grid 256 = 1 block/CU)
    gemm_bf16<0, false, __hip_bfloat16><<<(BT_ / BM) * (R_ / BN), 256, 0, stream>>>(
        xb, WqdT + (size_t)D_ * D_, bd, xdb, nullptr, BT_, R_, D_);
    // 2) q = elu1(x @ Wq + bq)   (256^2 8-phase; grid 256; nt=16)
    gemm_p8<1, false, __hip_bfloat16><<<(BT_ / PBM) * (D_ / PBN), 512, 0, stream>>>(
        xb, WqdT, bq, qb, BT_, D_, D_);
    // 3) kvT[j][t] = Wu^T @ xd^T + bu[j], elu1 rows (j&127)<64  (grid 512; nt=4)
    gemm_p8<2, true, __hip_bfloat16><<<(TWO_D_ / PBM) * (BT_ / PBN), 512, 0, stream>>>(
        WuT, xdb, bu, kvT, TWO_D_, BT_, R_);
    // 4) ctx + ksum via MFMA
    ctx_mfma<<<64 * (T_ / CHT), 256, 0, stream>>>(kvT, ctx, ksum);
    // 5) pack ctx -> bf16 transposed
    pack_ctx<<<64, 256, 0, stream>>>(ctx, ctxT);
    // 6) out = z * (q @ ctx)
    out_mfma<<<64 * 16, 256, 0, stream>>>(qb, ctxT, ksum, outb);
    // 7) final = outb @ Wo + bo   (256^2 8-phase; grid 256; nt=16)
    gemm_p8<0, false, float><<<(BT_ / PBM) * (D_ / PBN), 512, 0, stream>>>(
        outb, WoT, bo, out, BT_, D_, D_);
}

// Round 7
// 311.803 us; speedup vs baseline: 1.0780x; 1.0470x over previous
//
#include <hip/hip_runtime.h>
#include <hip/hip_bf16.h>
#include <cstddef>
#include <cstdint>

// Problem constants
#define B_  4
#define T_  4096
#define D_  1024
#define H_  16
#define DH_ 64
#define R_  256
#define BT_ (B_ * T_)       // 16384
#define TWO_D_ (2 * D_)     // 2048

typedef __attribute__((ext_vector_type(8))) short short8;
typedef __attribute__((ext_vector_type(4))) float f32x4;

__device__ __forceinline__ float elu1(float x) {
    return x > 0.0f ? x + 1.0f : __expf(x);
}

__device__ __forceinline__ float bf2f(short u) {
    union { uint32_t i; float f; } c;
    c.i = ((uint32_t)(uint16_t)u) << 16;
    return c.f;
}

typedef __attribute__((address_space(1))) void void_g;
typedef __attribute__((address_space(3))) void void_l;
__device__ __forceinline__ void gld_lds16(const void* g, void* l) {
    __builtin_amdgcn_global_load_lds(
        (const void_g*)(uintptr_t)g,
        (void_l*)(uint32_t)(uintptr_t)l,
        16, 0, 0);
}

__device__ __forceinline__ void store_out(float* p, float v) { *p = v; }
__device__ __forceinline__ void store_out(__hip_bfloat16* p, float v) { *p = __float2bfloat16(v); }

// ---------------------------------------------------------------------------
// 256x256 8-PHASE GEMM (T2+T3+T4+T5) with intra-phase split-drain.
// Identical barrier/stage/vmcnt structure to the round-6 PASSING kernel;
// the only change: each phase's ds_reads are issued ksl0-group first
// (order pinned by sched_barrier(0)), then lgkm(6/4/2) waits ONLY for the
// ksl0 operands -> 8 ksl0-MFMAs run while the ksl1 reads drain -> lgkm(0)
// -> 8 ksl1-MFMAs.  Accumulation order per acc element unchanged (k0,k1).
// ---------------------------------------------------------------------------
#define PBM 256
#define PBN 256

template<int EPI, bool BROW, typename OT>
__global__ __launch_bounds__(512, 2) void gemm_p8(
    const __hip_bfloat16* __restrict__ A,
    const __hip_bfloat16* __restrict__ Bt,
    const float* __restrict__ bias,
    OT* __restrict__ C,
    int M, int N, int K)
{
    __shared__ alignas(16) __hip_bfloat16 sm[65536];  // 128 KiB
    __hip_bfloat16* Asm = sm;            // 4 x 8192 (buf*2+half)
    __hip_bfloat16* Bsm = sm + 32768;

    const int nbx = N / PBN;
    const int nbm = M / PBM;
    const int sh = (nbm < 8) ? nbm : 8;
    const int id = blockIdx.x;
    const int wi = id % (sh * nbx);
    const int bm = ((id / (sh * nbx)) * sh + (wi % sh)) * PBM;
    const int bn = (wi / sh) * PBN;

    const int tid  = threadIdx.x;
    const int lane = tid & 63;
    const int w    = tid >> 6;
    const int wm   = w >> 2;        // 0..1
    const int wn   = w & 3;         // 0..3
    const int r15  = lane & 15;
    const int kg   = lane >> 4;

    const int nt = K / 64;          // K-tiles; even, >= 4 at all call sites

    // staging: chunk c -> row c>>3, k-group (c&7)^(row&7) (pre-swizzled src)
    const int rl = tid >> 3;
    const int g  = (tid & 7) ^ (rl & 7);
    const __hip_bfloat16* aS = A  + (size_t)(bm + rl) * K + g * 8;
    const __hip_bfloat16* bS = Bt + (size_t)(bn + rl) * K + g * 8;
    __hip_bfloat16* dA = Asm + tid * 8;
    __hip_bfloat16* dB = Bsm + tid * 8;

    auto stA = [&](int t, int h) {
        const int tc = (t < nt) ? t : (nt - 1);      // tail clamp
        __hip_bfloat16* d = dA + ((t & 1) * 2 + h) * 8192;
        const __hip_bfloat16* s = aS + (size_t)(h * 128) * K + tc * 64;
        gld_lds16(s, d);
        gld_lds16(s + (size_t)64 * K, d + 4096);
    };
    auto stB = [&](int t, int h) {
        const int tc = (t < nt) ? t : (nt - 1);
        __hip_bfloat16* d = dB + ((t & 1) * 2 + h) * 8192;
        const __hip_bfloat16* s = bS + (size_t)(h * 128) * K + tc * 64;
        gld_lds16(s, d);
        gld_lds16(s + (size_t)64 * K, d + 4096);
    };

    // fragment read bases (swizzled): elem-group xor (row&7)
    const int x3    = (r15 & 7) << 3;
    const int kofs0 = (kg * 8) ^ x3;
    const int kofs1 = (32 + kg * 8) ^ x3;
    const __hip_bfloat16* Af0 = Asm + wm * 8192 + r15 * 64;
    const __hip_bfloat16* Bf0 = Bsm + (wn >> 1) * 8192 + (wn & 1) * 4096 + r15 * 64;
    const __hip_bfloat16* Af1 = Af0 + 16384;
    const __hip_bfloat16* Bf1 = Bf0 + 16384;

    f32x4 acc[8][4] = {};
    short8 af[8][2], bf[4][2];

#define RDA(i, ks, BASE) af[i][ks] = *(const short8*)((BASE) + (i) * 1024 + ((ks) ? kofs1 : kofs0))
#define RDB(j, ks, BASE) bf[j][ks] = *(const short8*)((BASE) + (j) * 1024 + ((ks) ? kofs1 : kofs0))
#define MM(ILO, IHI, JLO, JHI, KS)                                             \
    _Pragma("unroll")                                                          \
    for (int i = (ILO); i < (IHI); ++i)                                        \
        _Pragma("unroll")                                                      \
        for (int j = (JLO); j < (JHI); ++j)                                    \
            acc[i][j] = __builtin_amdgcn_mfma_f32_16x16x32_bf16(af[i][KS], bf[j][KS], acc[i][j], 0, 0, 0)
#define SB0() __builtin_amdgcn_sched_barrier(0)

    // prologue: A(0), B(0), A(1); confirm tile 0; collective
    stA(0, 0); stA(0, 1); stB(0, 0); stB(0, 1); stA(1, 0); stA(1, 1);
    asm volatile("s_waitcnt vmcnt(4)" ::: "memory");
    __builtin_amdgcn_s_barrier();

    for (int t = 0; t < nt; t += 2) {
        // ================= tile t (buf0) =================
        // ph1: reads af03+bf01 (k0 group first) | stage B(t+1)h0
#pragma unroll
        for (int i = 0; i < 4; ++i) RDA(i, 0, Af0);
#pragma unroll
        for (int j = 0; j < 2; ++j) RDB(j, 0, Bf0);
        SB0();
#pragma unroll
        for (int i = 0; i < 4; ++i) RDA(i, 1, Af0);
#pragma unroll
        for (int j = 0; j < 2; ++j) RDB(j, 1, Bf0);
        stB(t + 1, 0);
        __builtin_amdgcn_s_barrier();
        asm volatile("s_waitcnt lgkmcnt(6)" ::: "memory");
        SB0();
        __builtin_amdgcn_s_setprio(1);
        MM(0, 4, 0, 2, 0);
        asm volatile("s_waitcnt lgkmcnt(0)" ::: "memory");
        SB0();
        MM(0, 4, 0, 2, 1);
        __builtin_amdgcn_s_setprio(0);
        __builtin_amdgcn_s_barrier();

        // ph2: reads af47 | stage B(t+1)h1
#pragma unroll
        for (int i = 4; i < 8; ++i) RDA(i, 0, Af0);
        SB0();
#pragma unroll
        for (int i = 4; i < 8; ++i) RDA(i, 1, Af0);
        stB(t + 1, 1);
        __builtin_amdgcn_s_barrier();
        asm volatile("s_waitcnt lgkmcnt(4)" ::: "memory");
        SB0();
        __builtin_amdgcn_s_setprio(1);
        MM(4, 8, 0, 2, 0);
        asm volatile("s_waitcnt lgkmcnt(0)" ::: "memory");
        SB0();
        MM(4, 8, 0, 2, 1);
        __builtin_amdgcn_s_setprio(0);
        __builtin_amdgcn_s_barrier();

        // ph3: reads bf23 | stage A(t+2)h0
#pragma unroll
        for (int j = 2; j < 4; ++j) RDB(j, 0, Bf0);
        SB0();
#pragma unroll
        for (int j = 2; j < 4; ++j) RDB(j, 1, Bf0);
        stA(t + 2, 0);
        __builtin_amdgcn_s_barrier();
        asm volatile("s_waitcnt lgkmcnt(2)" ::: "memory");
        SB0();
        __builtin_amdgcn_s_setprio(1);
        MM(4, 8, 2, 4, 0);
        asm volatile("s_waitcnt lgkmcnt(0)" ::: "memory");
        SB0();
        MM(4, 8, 2, 4, 1);
        __builtin_amdgcn_s_setprio(0);
        __builtin_amdgcn_s_barrier();

        // ph4: stage A(t+2)h1 | vmcnt(4)
        stA(t + 2, 1);
        asm volatile("s_waitcnt vmcnt(4)" ::: "memory");
        __builtin_amdgcn_s_barrier();
        SB0();
        __builtin_amdgcn_s_setprio(1);
        MM(0, 4, 2, 4, 0);
        MM(0, 4, 2, 4, 1);
        __builtin_amdgcn_s_setprio(0);
        __builtin_amdgcn_s_barrier();

        // ================= tile t+1 (buf1) =================
        // ph5: reads af03+bf01 | stage B(t+2)h0
#pragma unroll
        for (int i = 0; i < 4; ++i) RDA(i, 0, Af1);
#pragma unroll
        for (int j = 0; j < 2; ++j) RDB(j, 0, Bf1);
        SB0();
#pragma unroll
        for (int i = 0; i < 4; ++i) RDA(i, 1, Af1);
#pragma unroll
        for (int j = 0; j < 2; ++j) RDB(j, 1, Bf1);
        stB(t + 2, 0);
        __builtin_amdgcn_s_barrier();
        asm volatile("s_waitcnt lgkmcnt(6)" ::: "memory");
        SB0();
        __builtin_amdgcn_s_setprio(1);
        MM(0, 4, 0, 2, 0);
        asm volatile("s_waitcnt lgkmcnt(0)" ::: "memory");
        SB0();
        MM(0, 4, 0, 2, 1);
        __builtin_amdgcn_s_setprio(0);
        __builtin_amdgcn_s_barrier();

        // ph6: reads af47 | stage B(t+2)h1
#pragma unroll
        for (int i = 4; i < 8; ++i) RDA(i, 0, Af1);
        SB0();
#pragma unroll
        for (int i = 4; i < 8; ++i) RDA(i, 1, Af1);
        stB(t + 2, 1);
        __builtin_amdgcn_s_barrier();
        asm volatile("s_waitcnt lgkmcnt(4)" ::: "memory");
        SB0();
        __builtin_amdgcn_s_setprio(1);
        MM(4, 8, 0, 2, 0);
        asm volatile("s_waitcnt lgkmcnt(0)" ::: "memory");
        SB0();
        MM(4, 8, 0, 2, 1);
        __builtin_amdgcn_s_setprio(0);
        __builtin_amdgcn_s_barrier();

        // ph7: reads bf23 | stage A(t+3)h0
#pragma unroll
        for (int j = 2; j < 4; ++j) RDB(j, 0, Bf1);
        SB0();
#pragma unroll
        for (int j = 2; j < 4; ++j) RDB(j, 1, Bf1);
        stA(t + 3, 0);
        __builtin_amdgcn_s_barrier();
        asm volatile("s_waitcnt lgkmcnt(2)" ::: "memory");
        SB0();
        __builtin_amdgcn_s_setprio(1);
        MM(4, 8, 2, 4, 0);
        asm volatile("s_waitcnt lgkmcnt(0)" ::: "memory");
        SB0();
        MM(4, 8, 2, 4, 1);
        __builtin_amdgcn_s_setprio(0);
        __builtin_amdgcn_s_barrier();

        // ph8: stage A(t+3)h1 | vmcnt(4)
        stA(t + 3, 1);
        asm volatile("s_waitcnt vmcnt(4)" ::: "memory");
        __builtin_amdgcn_s_barrier();
        SB0();
        __builtin_amdgcn_s_setprio(1);
        MM(0, 4, 2, 4, 0);
        MM(0, 4, 2, 4, 1);
        __builtin_amdgcn_s_setprio(0);
        __builtin_amdgcn_s_barrier();
    }
    asm volatile("s_waitcnt vmcnt(0)" ::: "memory");   // drain tail DMA

#undef RDA
#undef RDB
#undef MM
#undef SB0

    // epilogue; C/D layout: col=lane&15, row=(lane>>4)*4+reg  [m89-verified]
    const int row0 = bm + wm * 128 + (lane >> 4) * 4;

    float brow[8][4];
    if (BROW) {
#pragma unroll
        for (int i = 0; i < 8; ++i)
#pragma unroll
            for (int r = 0; r < 4; ++r) brow[i][r] = bias[row0 + i * 16 + r];
    }
#pragma unroll
    for (int j = 0; j < 4; ++j) {
        const int col = bn + wn * 64 + j * 16 + r15;
        const float bv = BROW ? 0.0f : bias[col];
        const bool kp_col = ((col & 127) < 64);
#pragma unroll
        for (int i = 0; i < 8; ++i) {
#pragma unroll
            for (int r = 0; r < 4; ++r) {
                const int row = row0 + i * 16 + r;
                float v = acc[i][j][r] + (BROW ? brow[i][r] : bv);
                if (EPI == 1) v = elu1(v);
                else if (EPI == 2) {
                    const bool kp = BROW ? ((row & 127) < 64) : kp_col;
                    if (kp) v = elu1(v);
                }
                store_out(C + (size_t)row * N + col, v);
            }
        }
    }
}

// ---------------------------------------------------------------------------
// OLD 128x128 ring GEMM (hardware-validated round 1) — kept for xd (N=256).
// ---------------------------------------------------------------------------
#define BM 128
#define BN 128
#define BK 32
#define NBUF 5

template<int EPI, bool BROW, typename OT>
__global__ __launch_bounds__(256) void gemm_bf16(
    const __hip_bfloat16* __restrict__ A,
    const __hip_bfloat16* __restrict__ Bt,
    const float* __restrict__ bias,
    OT* __restrict__ C,
    OT* __restrict__ C2,
    int M, int N, int K)
{
    __shared__ alignas(16) __hip_bfloat16 As[NBUF * BM * BK];
    __shared__ alignas(16) __hip_bfloat16 Bs[NBUF * BN * BK];

    const int nbx = N / BN;
    const int id = blockIdx.x;
    const int strip = id / (8 * nbx);
    const int wi = id % (8 * nbx);
    const int bm = (strip * 8 + (wi & 7)) * BM;
    const int bn = (wi >> 3) * BN;

    const int tid  = threadIdx.x;
    const int lane = tid & 63;
    const int wm   = (tid >> 7) * 64;
    const int wn   = ((tid >> 6) & 1) * 64;
    const int r15  = lane & 15;
    const int kg   = lane >> 4;

    f32x4 acc[4][4] = {};

    const int c0 = tid, c1 = tid + 256;
    const __hip_bfloat16* a0 = A  + (size_t)(bm + (c0 >> 2)) * K + (c0 & 3) * 8;
    const __hip_bfloat16* a1 = A  + (size_t)(bm + (c1 >> 2)) * K + (c1 & 3) * 8;
    const __hip_bfloat16* b0 = Bt + (size_t)(bn + (c0 >> 2)) * K + (c0 & 3) * 8;
    const __hip_bfloat16* b1 = Bt + (size_t)(bn + (c1 >> 2)) * K + (c1 & 3) * 8;

    const int nk = K / BK;

    auto stage = [&](int t) {
        const int buf = t % NBUF;
        __hip_bfloat16* Ad = As + buf * (BM * BK);
        __hip_bfloat16* Bd = Bs + buf * (BN * BK);
        const int k0 = t * BK;
        gld_lds16(a0 + k0, Ad + c0 * 8);
        gld_lds16(a1 + k0, Ad + c1 * 8);
        gld_lds16(b0 + k0, Bd + c0 * 8);
        gld_lds16(b1 + k0, Bd + c1 * 8);
    };

    stage(0); stage(1); stage(2);

    for (int t = 0; t < nk; ++t) {
        if (t + 3 < nk) {
            stage(t + 3);
            asm volatile("s_waitcnt vmcnt(12)\ns_barrier" ::: "memory");
        } else if (t + 2 < nk) {
            asm volatile("s_waitcnt vmcnt(8)\ns_barrier" ::: "memory");
        } else if (t + 1 < nk) {
            asm volatile("s_waitcnt vmcnt(4)\ns_barrier" ::: "memory");
        } else {
            asm volatile("s_waitcnt vmcnt(0)\ns_barrier" ::: "memory");
        }

        const __hip_bfloat16* Asb = As + (t % NBUF) * (BM * BK);
        const __hip_bfloat16* Bsb = Bs + (t % NBUF) * (BN * BK);

        short8 af[4], bf[4];
#pragma unroll
        for (int i = 0; i < 4; ++i) {
            af[i] = *(const short8*)(Asb + (wm + i * 16 + r15) * BK + kg * 8);
            bf[i] = *(const short8*)(Bsb + (wn + i * 16 + r15) * BK + kg * 8);
        }
#pragma unroll
        for (int i = 0; i < 4; ++i)
#pragma unroll
            for (int j = 0; j < 4; ++j)
                acc[i][j] = __builtin_amdgcn_mfma_f32_16x16x32_bf16(af[i], bf[j], acc[i][j], 0, 0, 0);
    }

    const int row0 = bm + wm + (lane >> 4) * 4;

    if (EPI == 3) {
        const bool qreg = (bn < 1024);
#pragma unroll
        for (int j = 0; j < 4; ++j) {
            const int col = bn + wn + j * 16 + r15;
            const float bv = bias[col];
#pragma unroll
            for (int i = 0; i < 4; ++i)
#pragma unroll
                for (int r = 0; r < 4; ++r) {
                    const int row = row0 + i * 16 + r;
                    float v = acc[i][j][r] + bv;
                    if (qreg) {
                        store_out(C + (size_t)row * 1024 + col, elu1(v));
                    } else {
                        store_out(C2 + (size_t)row * 256 + (col - 1024), v);
                    }
                }
        }
        return;
    }

    float brow[4][4];
    if (BROW) {
#pragma unroll
        for (int i = 0; i < 4; ++i)
#pragma unroll
            for (int r = 0; r < 4; ++r) brow[i][r] = bias[row0 + i * 16 + r];
    }
#pragma unroll
    for (int j = 0; j < 4; ++j) {
        const int col = bn + wn + j * 16 + r15;
        const float bv = BROW ? 0.0f : bias[col];
        const bool kp_col = ((col & 127) < 64);
#pragma unroll
        for (int i = 0; i < 4; ++i) {
#pragma unroll
            for (int r = 0; r < 4; ++r) {
                const int row = row0 + i * 16 + r;
                float v = acc[i][j][r] + (BROW ? brow[i][r] : bv);
                if (EPI == 1) v = elu1(v);
                else if (EPI == 2) {
                    const bool kp = BROW ? ((row & 127) < 64) : kp_col;
                    if (kp) v = elu1(v);
                }
                store_out(C + (size_t)row * N + col, v);
            }
        }
    }
}

// ---------------------------------------------------------------------------
// prep: fused preprocessing — cast x->bf16, 4 weight transpose-casts, and
// zeroing of ctx/ksum — one dispatch, branch by block range.
// ---------------------------------------------------------------------------
__device__ __forceinline__ void tcast_body(
    const float* __restrict__ W, __hip_bfloat16* __restrict__ Wt,
    int K, int N, int bx, int by, int tid, float (*t)[33])
{
    const int n0 = bx * 32, k0 = by * 32;
    const int c = tid & 31, r = tid >> 5;
#pragma unroll
    for (int rr = r; rr < 32; rr += 8)
        t[rr][c] = W[(size_t)(k0 + rr) * N + n0 + c];
    __syncthreads();
#pragma unroll
    for (int rr = r; rr < 32; rr += 8)
        Wt[(size_t)(n0 + rr) * K + k0 + c] = __float2bfloat16(t[c][rr]);
}

__global__ __launch_bounds__(256) void prep(
    const float* __restrict__ x,
    const float* __restrict__ Wq, const float* __restrict__ Wd,
    const float* __restrict__ Wu, const float* __restrict__ Wo,
    __hip_bfloat16* __restrict__ xb,
    __hip_bfloat16* __restrict__ WqdT, __hip_bfloat16* __restrict__ WuT,
    __hip_bfloat16* __restrict__ WoT,
    float* __restrict__ zbase)
{
    __shared__ float t[32][33];
    const int id = blockIdx.x;
    const int tid = threadIdx.x;

    if (id < 8192) {                       // cast x -> xb (bf16x8)
        const int i = (id * 256 + tid) * 8;
        float4 v0 = *(const float4*)(x + i);
        float4 v1 = *(const float4*)(x + i + 4);
        __hip_bfloat16 tt[8];
        tt[0] = __float2bfloat16(v0.x); tt[1] = __float2bfloat16(v0.y);
        tt[2] = __float2bfloat16(v0.z); tt[3] = __float2bfloat16(v0.w);
        tt[4] = __float2bfloat16(v1.x); tt[5] = __float2bfloat16(v1.y);
        tt[6] = __float2bfloat16(v1.z); tt[7] = __float2bfloat16(v1.w);
        *(short8*)(xb + i) = *(const short8*)tt;
    } else if (id < 8192 + 1024) {         // Wq [1024,1024] -> WqdT
        const int u = id - 8192;
        tcast_body(Wq, WqdT, D_, D_, u & 31, u >> 5, tid, t);
    } else if (id < 8192 + 1280) {         // Wd [1024,256] -> WqdT+1024*1024
        const int u = id - (8192 + 1024);
        tcast_body(Wd, WqdT + (size_t)D_ * D_, D_, R_, u & 7, u >> 3, tid, t);
    } else if (id < 8192 + 1792) {         // Wu [256,2048] -> WuT
        const int u = id - (8192 + 1280);
        tcast_body(Wu, WuT, R_, TWO_D_, u & 63, u >> 6, tid, t);
    } else if (id < 8192 + 2816) {         // Wo [1024,1024] -> WoT
        const int u = id - (8192 + 1792);
        tcast_body(Wo, WoT, D_, D_, u & 31, u >> 5, tid, t);
    } else {                               // zero ctx+ksum (266240 floats)
        const int u = id - (8192 + 2816);
        const int i = (u * 256 + tid) * 8;
        float4 z = {0.f, 0.f, 0.f, 0.f};
        *(float4*)(zbase + i) = z;
        *(float4*)(zbase + i + 4) = z;
    }
}

// ---------------------------------------------------------------------------
// ctx_mfma: ctx[bh][d][e] = sum_t K^T[d][t] * V^T[e][t]; ksum via ones-trick.
// ---------------------------------------------------------------------------
#define CHT 512

__global__ __launch_bounds__(256) void ctx_mfma(
    const __hip_bfloat16* __restrict__ kvT, float* __restrict__ ctx,
    float* __restrict__ ksum)
{
    __shared__ alignas(16) unsigned char smem[40960];
    float* red0 = (float*)smem;
    float* red1 = (float*)(smem + 20480);

    const int bh = blockIdx.x >> 3;
    const int chunk = blockIdx.x & 7;
    const int b = bh >> 4;
    const int h = bh & 15;
    const int tid = threadIdx.x;
    const int lane = tid & 63;
    const int w = tid >> 6;
    const int r15 = lane & 15;
    const int kg  = lane >> 4;

    f32x4 acc[4][4] = {};
    f32x4 acc4[4] = {};

    const short one = (short)0x3F80;
    const short8 bfv = (r15 == 0)
        ? (short8){one, one, one, one, one, one, one, one}
        : (short8){0, 0, 0, 0, 0, 0, 0, 0};

    const size_t tbase = (size_t)b * T_ + (size_t)chunk * CHT;
    const __hip_bfloat16* src = kvT + (size_t)(h * 128) * BT_ + tbase;

    for (int it = 0; it < CHT / 128; ++it) {
#pragma unroll
        for (int r = 0; r < 8; ++r) {
            const int c = r * 256 + tid;
            const int s = c >> 9, j = (c >> 2) & 127, u = c & 3;
            gld_lds16(src + (size_t)j * BT_ + it * 128 + s * 32 + u * 8,
                      smem + c * 16);
        }
        __syncthreads();

        const __hip_bfloat16* Ls = (const __hip_bfloat16*)smem;
        short8 af[4], bf[4];
#pragma unroll
        for (int i = 0; i < 4; ++i) {
            af[i] = *(const short8*)(Ls + (w * 128 + i * 16 + r15) * 32 + kg * 8);
            bf[i] = *(const short8*)(Ls + (w * 128 + 64 + i * 16 + r15) * 32 + kg * 8);
        }
#pragma unroll
        for (int i = 0; i < 4; ++i) {
#pragma unroll
            for (int j = 0; j < 4; ++j)
                acc[i][j] = __builtin_amdgcn_mfma_f32_16x16x32_bf16(af[i], bf[j], acc[i][j], 0, 0, 0);
            acc4[i] = __builtin_amdgcn_mfma_f32_16x16x32_bf16(af[i], bfv, acc4[i], 0, 0, 0);
        }
        __syncthreads();
    }

    const int q4 = lane >> 4;
    auto wr = [&](float* reg) {
#pragma unroll
        for (int i = 0; i < 4; ++i) {
#pragma unroll
            for (int r = 0; r < 4; ++r) {
                const int row = i * 16 + q4 * 4 + r;
#pragma unroll
                for (int j = 0; j < 4; ++j) reg[row * 80 + j * 16 + r15] = acc[i][j][r];
                reg[row * 80 + 64 + r15] = acc4[i][r];
            }
        }
    };
    auto rd = [&](const float* reg) {
#pragma unroll
        for (int i = 0; i < 4; ++i) {
#pragma unroll
            for (int r = 0; r < 4; ++r) {
                const int row = i * 16 + q4 * 4 + r;
#pragma unroll
                for (int j = 0; j < 4; ++j) acc[i][j][r] += reg[row * 80 + j * 16 + r15];
                acc4[i][r] += reg[row * 80 + 64 + r15];
            }
        }
    };

    if (w == 1) wr(red0);
    if (w == 3) wr(red1);
    __syncthreads();
    if (w == 0) rd(red0);
    if (w == 2) rd(red1);
    __syncthreads();
    if (w == 2) wr(red0);
    __syncthreads();
    if (w == 0) { rd(red0); wr(red0); }
    __syncthreads();

    float* cdst = ctx + (size_t)bh * 4096;
#pragma unroll
    for (int r = 0; r < 16; ++r) {
        const int idx = r * 256 + tid;
        const int d = idx >> 6, e = idx & 63;
        atomicAdd(cdst + idx, red0[d * 80 + e]);
    }
    if (tid < 64) atomicAdd(ksum + bh * 64 + tid, red0[tid * 80 + 64]);
}

// ---------------------------------------------------------------------------
__global__ __launch_bounds__(256) void pack_ctx(
    const float* __restrict__ ctx, __hip_bfloat16* __restrict__ ctxT)
{
    __shared__ float L[64 * 65];
    const int bh = blockIdx.x;
    const int tid = threadIdx.x;
#pragma unroll
    for (int r = 0; r < 16; ++r) {
        const int idx = r * 256 + tid;
        L[(idx >> 6) * 65 + (idx & 63)] = ctx[(size_t)bh * 4096 + idx];
    }
    __syncthreads();
#pragma unroll
    for (int r = 0; r < 16; ++r) {
        const int idx = r * 256 + tid;
        ctxT[(size_t)bh * 4096 + idx] =
            __float2bfloat16(L[(idx & 63) * 65 + (idx >> 6)]);
    }
}

// ---------------------------------------------------------------------------
// out_mfma: out[t][h*64+e] = z_t * sum_d q[t][d] * ctx[d][e]
// ---------------------------------------------------------------------------
__global__ __launch_bounds__(256) void out_mfma(
    const __hip_bfloat16* __restrict__ qb, const __hip_bfloat16* __restrict__ ctxT,
    const float* __restrict__ ksum, __hip_bfloat16* __restrict__ outb)
{
    __shared__ alignas(16) unsigned char As[256 * 128];
    __shared__ alignas(16) unsigned char Bs[64 * 128];
    __shared__ float ksumL[64];
    __shared__ float zbuf[256];

    const int bh = blockIdx.x >> 4;
    const int tile = blockIdx.x & 15;
    const int b = bh >> 4;
    const int h = bh & 15;
    const int tid = threadIdx.x;
    const int lane = tid & 63;
    const int w = tid >> 6;
    const int r15 = lane & 15;
    const int kg  = lane >> 4;

    const size_t trow0 = (size_t)b * T_ + (size_t)tile * 256;

#pragma unroll
    for (int r = 0; r < 8; ++r) {
        const int c = r * 256 + tid;
        const int row = c >> 3, slot = c & 7, u = slot ^ (row & 7);
        gld_lds16(qb + (trow0 + row) * D_ + h * 64 + u * 8, As + c * 16);
    }
#pragma unroll
    for (int r = 0; r < 2; ++r) {
        const int c = r * 256 + tid;
        const int row = c >> 3, slot = c & 7, u = slot ^ (row & 7);
        gld_lds16(ctxT + (size_t)bh * 4096 + row * 64 + u * 8, Bs + c * 16);
    }
    if (tid < 64) ksumL[tid] = ksum[bh * 64 + tid];
    __syncthreads();

    short8 af[4][2], bf[4][2];
#pragma unroll
    for (int i = 0; i < 4; ++i)
#pragma unroll
        for (int s = 0; s < 2; ++s) {
            const int m = w * 64 + i * 16 + r15;
            const int n = i * 16 + r15;
            const int uk = s * 4 + kg;
            af[i][s] = *(const short8*)(As + m * 128 + ((uk ^ (m & 7)) * 16));
            bf[i][s] = *(const short8*)(Bs + n * 128 + ((uk ^ (n & 7)) * 16));
        }

    f32x4 acc[4][4] = {};
#pragma unroll
    for (int s = 0; s < 2; ++s)
#pragma unroll
        for (int i = 0; i < 4; ++i)
#pragma unroll
            for (int j = 0; j < 4; ++j)
                acc[i][j] = __builtin_amdgcn_mfma_f32_16x16x32_bf16(af[i][s], bf[j][s], acc[i][j], 0, 0, 0);

    float dsum[4];
#pragma unroll
    for (int i = 0; i < 4; ++i) {
        float s0 = 0.0f;
#pragma unroll
        for (int s = 0; s < 2; ++s)
#pragma unroll
            for (int j8 = 0; j8 < 8; ++j8)
                s0 += bf2f(af[i][s][j8]) * ksumL[s * 32 + kg * 8 + j8];
        s0 += __shfl_xor(s0, 16);
        s0 += __shfl_xor(s0, 32);
        dsum[i] = s0;
    }
    if (lane < 16) {
#pragma unroll
        for (int i = 0; i < 4; ++i)
            zbuf[w * 64 + i * 16 + lane] = 1.0f / (dsum[i] + 1e-6f);
    }
    __syncthreads();

    const int q4 = lane >> 4;
#pragma unroll
    for (int i = 0; i < 4; ++i) {
#pragma unroll
        for (int r = 0; r < 4; ++r) {
            const int m = w * 64 + i * 16 + q4 * 4 + r;
            const float z = zbuf[m];
#pragma unroll
            for (int j = 0; j < 4; ++j) {
                outb[(trow0 + m) * D_ + h * 64 + j * 16 + r15] =
                    __float2bfloat16(acc[i][j][r] * z);
            }
        }
    }
}

// ---------------------------------------------------------------------------
extern "C" void kernel_launch(void* const* d_in, const int* in_sizes, int n_in,
                              void* d_out, int out_size, void* d_ws, size_t ws_size,
                              hipStream_t stream) {
    const float* x  = (const float*)d_in[0];
    const float* Wq = (const float*)d_in[1];
    const float* bq = (const float*)d_in[2];
    const float* Wd = (const float*)d_in[3];
    const float* bd = (const float*)d_in[4];
    const float* Wu = (const float*)d_in[5];
    const float* bu = (const float*)d_in[6];
    const float* Wo = (const float*)d_in[7];
    const float* bo = (const float*)d_in[8];
    float* out = (float*)d_out;

    __hip_bfloat16* xb    = (__hip_bfloat16*)d_ws;            // BT*D
    __hip_bfloat16* WqdT  = xb    + (size_t)BT_ * D_;         // [1280][1024]
    __hip_bfloat16* WuT   = WqdT  + (size_t)1280 * D_;        // [2048][256]
    __hip_bfloat16* WoT   = WuT   + (size_t)TWO_D_ * R_;      // [1024][1024]
    __hip_bfloat16* xdb   = WoT   + (size_t)D_ * D_;          // BT*R
    __hip_bfloat16* kvT   = xdb   + (size_t)BT_ * R_;         // 2048*BT
    __hip_bfloat16* qb    = kvT   + (size_t)TWO_D_ * BT_;     // BT*D
    float* bias_qd = (float*)(qb + (size_t)BT_ * D_);         // 1280 (unused)
    float* ctx  = bias_qd + 1280;                             // 64*4096
    float* ksum = ctx + (size_t)B_ * H_ * DH_ * DH_;          // 64*64
    __hip_bfloat16* ctxT = (__hip_bfloat16*)(ksum + B_ * H_ * DH_);  // 64*4096
    __hip_bfloat16* outb = xb;   // alias: xb dead after q/xd GEMMs

    // fused preprocessing: cast + 4 transposes + zero(ctx,ksum)
    prep<<<8192 + 2816 + 130, 256, 0, stream>>>(
        x, Wq, Wd, Wu, Wo, xb, WqdT, WuT, WoT, ctx);

    // 1) xd = x @ Wd + bd    (128^2 ring; grid 256 = 1 block/CU)
    gemm_bf16<0, false, __hip_bfloat16><<<(BT_ / BM) * (R_ / BN), 256, 0, stream>>>(
        xb, WqdT + (size_t)D_ * D_, bd, xdb, nullptr, BT_, R_, D_);
    // 2) q = elu1(x @ Wq + bq)   (256^2 8-phase; grid 256; nt=16)
    gemm_p8<1, false, __hip_bfloat16><<<(BT_ / PBM) * (D_ / PBN), 512, 0, stream>>>(
        xb, WqdT, bq, qb, BT_, D_, D_);
    // 3) kvT[j][t] = Wu^T @ xd^T + bu[j], elu1 rows (j&127)<64  (grid 512; nt=4)
    gemm_p8<2, true, __hip_bfloat16><<<(TWO_D_ / PBM) * (BT_ / PBN), 512, 0, stream>>>(
        WuT, xdb, bu, kvT, TWO_D_, BT_, R_);
    // 4) ctx + ksum via MFMA
    ctx_mfma<<<64 * (T_ / CHT), 256, 0, stream>>>(kvT, ctx, ksum);
    // 5) pack ctx -> bf16 transposed
    pack_ctx<<<64, 256, 0, stream>>>(ctx, ctxT);
    // 6) out = z * (q @ ctx)
    out_mfma<<<64 * 16, 256, 0, stream>>>(qb, ctxT, ksum, outb);
    // 7) final = outb @ Wo + bo   (256^2 8-phase; grid 256; nt=16)
    gemm_p8<0, false, float><<<(BT_ / PBM) * (D_ / PBN), 512, 0, stream>>>(
        outb, WoT, bo, out, BT_, D_, D_);
}

// Round 8
// 300.767 us; speedup vs baseline: 1.1175x; 1.0367x over previous
//
#include <hip/hip_runtime.h>
#include <hip/hip_bf16.h>
#include <cstddef>
#include <cstdint>

// Problem constants
#define B_  4
#define T_  4096
#define D_  1024
#define H_  16
#define DH_ 64
#define R_  256
#define BT_ (B_ * T_)       // 16384
#define TWO_D_ (2 * D_)     // 2048

typedef __attribute__((ext_vector_type(8))) short short8;
typedef __attribute__((ext_vector_type(4))) float f32x4;

__device__ __forceinline__ float elu1(float x) {
    return x > 0.0f ? x + 1.0f : __expf(x);
}

__device__ __forceinline__ float bf2f(short u) {
    union { uint32_t i; float f; } c;
    c.i = ((uint32_t)(uint16_t)u) << 16;
    return c.f;
}

typedef __attribute__((address_space(1))) void void_g;
typedef __attribute__((address_space(3))) void void_l;
__device__ __forceinline__ void gld_lds16(const void* g, void* l) {
    __builtin_amdgcn_global_load_lds(
        (const void_g*)(uintptr_t)g,
        (void_l*)(uint32_t)(uintptr_t)l,
        16, 0, 0);
}

__device__ __forceinline__ void store_out(float* p, float v) { *p = v; }
__device__ __forceinline__ void store_out(__hip_bfloat16* p, float v) { *p = __float2bfloat16(v); }

// ---------------------------------------------------------------------------
// 256x256 8-PHASE GEMM (T2+T3+T4+T5) with intra-phase split-drain.
// (round-7 validated kernel, unchanged)
// ---------------------------------------------------------------------------
#define PBM 256
#define PBN 256

#define RDA(i, ks, BASE) af[i][ks] = *(const short8*)((BASE) + (i) * 1024 + ((ks) ? kofs1 : kofs0))
#define RDB(j, ks, BASE) bf[j][ks] = *(const short8*)((BASE) + (j) * 1024 + ((ks) ? kofs1 : kofs0))
#define MM(ILO, IHI, JLO, JHI, KS)                                             \
    _Pragma("unroll")                                                          \
    for (int i = (ILO); i < (IHI); ++i)                                        \
        _Pragma("unroll")                                                      \
        for (int j = (JLO); j < (JHI); ++j)                                    \
            acc[i][j] = __builtin_amdgcn_mfma_f32_16x16x32_bf16(af[i][KS], bf[j][KS], acc[i][j], 0, 0, 0)
#define SB0() __builtin_amdgcn_sched_barrier(0)

// The 8-phase K-loop, shared verbatim between gemm_p8 and gemm3_ctx.
#define P8_KLOOP(AF0, BF0, AF1, BF1)                                           \
    for (int t = 0; t < nt; t += 2) {                                          \
        _Pragma("unroll")                                                      \
        for (int i = 0; i < 4; ++i) RDA(i, 0, AF0);                            \
        _Pragma("unroll")                                                      \
        for (int j = 0; j < 2; ++j) RDB(j, 0, BF0);                            \
        SB0();                                                                 \
        _Pragma("unroll")                                                      \
        for (int i = 0; i < 4; ++i) RDA(i, 1, AF0);                            \
        _Pragma("unroll")                                                      \
        for (int j = 0; j < 2; ++j) RDB(j, 1, BF0);                            \
        stB(t + 1, 0);                                                         \
        __builtin_amdgcn_s_barrier();                                          \
        asm volatile("s_waitcnt lgkmcnt(6)" ::: "memory");                     \
        SB0();                                                                 \
        __builtin_amdgcn_s_setprio(1);                                         \
        MM(0, 4, 0, 2, 0);                                                     \
        asm volatile("s_waitcnt lgkmcnt(0)" ::: "memory");                     \
        SB0();                                                                 \
        MM(0, 4, 0, 2, 1);                                                     \
        __builtin_amdgcn_s_setprio(0);                                         \
        __builtin_amdgcn_s_barrier();                                          \
        _Pragma("unroll")                                                      \
        for (int i = 4; i < 8; ++i) RDA(i, 0, AF0);                            \
        SB0();                                                                 \
        _Pragma("unroll")                                                      \
        for (int i = 4; i < 8; ++i) RDA(i, 1, AF0);                            \
        stB(t + 1, 1);                                                         \
        __builtin_amdgcn_s_barrier();                                          \
        asm volatile("s_waitcnt lgkmcnt(4)" ::: "memory");                     \
        SB0();                                                                 \
        __builtin_amdgcn_s_setprio(1);                                         \
        MM(4, 8, 0, 2, 0);                                                     \
        asm volatile("s_waitcnt lgkmcnt(0)" ::: "memory");                     \
        SB0();                                                                 \
        MM(4, 8, 0, 2, 1);                                                     \
        __builtin_amdgcn_s_setprio(0);                                         \
        __builtin_amdgcn_s_barrier();                                          \
        _Pragma("unroll")                                                      \
        for (int j = 2; j < 4; ++j) RDB(j, 0, BF0);                            \
        SB0();                                                                 \
        _Pragma("unroll")                                                      \
        for (int j = 2; j < 4; ++j) RDB(j, 1, BF0);                            \
        stA(t + 2, 0);                                                         \
        __builtin_amdgcn_s_barrier();                                          \
        asm volatile("s_waitcnt lgkmcnt(2)" ::: "memory");                     \
        SB0();                                                                 \
        __builtin_amdgcn_s_setprio(1);                                         \
        MM(4, 8, 2, 4, 0);                                                     \
        asm volatile("s_waitcnt lgkmcnt(0)" ::: "memory");                     \
        SB0();                                                                 \
        MM(4, 8, 2, 4, 1);                                                     \
        __builtin_amdgcn_s_setprio(0);                                         \
        __builtin_amdgcn_s_barrier();                                          \
        stA(t + 2, 1);                                                         \
        asm volatile("s_waitcnt vmcnt(4)" ::: "memory");                       \
        __builtin_amdgcn_s_barrier();                                          \
        SB0();                                                                 \
        __builtin_amdgcn_s_setprio(1);                                         \
        MM(0, 4, 2, 4, 0);                                                     \
        MM(0, 4, 2, 4, 1);                                                     \
        __builtin_amdgcn_s_setprio(0);                                         \
        __builtin_amdgcn_s_barrier();                                          \
        _Pragma("unroll")                                                      \
        for (int i = 0; i < 4; ++i) RDA(i, 0, AF1);                            \
        _Pragma("unroll")                                                      \
        for (int j = 0; j < 2; ++j) RDB(j, 0, BF1);                            \
        SB0();                                                                 \
        _Pragma("unroll")                                                      \
        for (int i = 0; i < 4; ++i) RDA(i, 1, AF1);                            \
        _Pragma("unroll")                                                      \
        for (int j = 0; j < 2; ++j) RDB(j, 1, BF1);                            \
        stB(t + 2, 0);                                                         \
        __builtin_amdgcn_s_barrier();                                          \
        asm volatile("s_waitcnt lgkmcnt(6)" ::: "memory");                     \
        SB0();                                                                 \
        __builtin_amdgcn_s_setprio(1);                                         \
        MM(0, 4, 0, 2, 0);                                                     \
        asm volatile("s_waitcnt lgkmcnt(0)" ::: "memory");                     \
        SB0();                                                                 \
        MM(0, 4, 0, 2, 1);                                                     \
        __builtin_amdgcn_s_setprio(0);                                         \
        __builtin_amdgcn_s_barrier();                                          \
        _Pragma("unroll")                                                      \
        for (int i = 4; i < 8; ++i) RDA(i, 0, AF1);                            \
        SB0();                                                                 \
        _Pragma("unroll")                                                      \
        for (int i = 4; i < 8; ++i) RDA(i, 1, AF1);                            \
        stB(t + 2, 1);                                                         \
        __builtin_amdgcn_s_barrier();                                          \
        asm volatile("s_waitcnt lgkmcnt(4)" ::: "memory");                     \
        SB0();                                                                 \
        __builtin_amdgcn_s_setprio(1);                                         \
        MM(4, 8, 0, 2, 0);                                                     \
        asm volatile("s_waitcnt lgkmcnt(0)" ::: "memory");                     \
        SB0();                                                                 \
        MM(4, 8, 0, 2, 1);                                                     \
        __builtin_amdgcn_s_setprio(0);                                         \
        __builtin_amdgcn_s_barrier();                                          \
        _Pragma("unroll")                                                      \
        for (int j = 2; j < 4; ++j) RDB(j, 0, BF1);                            \
        SB0();                                                                 \
        _Pragma("unroll")                                                      \
        for (int j = 2; j < 4; ++j) RDB(j, 1, BF1);                            \
        stA(t + 3, 0);                                                         \
        __builtin_amdgcn_s_barrier();                                          \
        asm volatile("s_waitcnt lgkmcnt(2)" ::: "memory");                     \
        SB0();                                                                 \
        __builtin_amdgcn_s_setprio(1);                                         \
        MM(4, 8, 2, 4, 0);                                                     \
        asm volatile("s_waitcnt lgkmcnt(0)" ::: "memory");                     \
        SB0();                                                                 \
        MM(4, 8, 2, 4, 1);                                                     \
        __builtin_amdgcn_s_setprio(0);                                         \
        __builtin_amdgcn_s_barrier();                                          \
        stA(t + 3, 1);                                                         \
        asm volatile("s_waitcnt vmcnt(4)" ::: "memory");                       \
        __builtin_amdgcn_s_barrier();                                          \
        SB0();                                                                 \
        __builtin_amdgcn_s_setprio(1);                                         \
        MM(0, 4, 2, 4, 0);                                                     \
        MM(0, 4, 2, 4, 1);                                                     \
        __builtin_amdgcn_s_setprio(0);                                         \
        __builtin_amdgcn_s_barrier();                                          \
    }

template<int EPI, bool BROW, typename OT>
__global__ __launch_bounds__(512, 2) void gemm_p8(
    const __hip_bfloat16* __restrict__ A,
    const __hip_bfloat16* __restrict__ Bt,
    const float* __restrict__ bias,
    OT* __restrict__ C,
    int M, int N, int K)
{
    __shared__ alignas(16) __hip_bfloat16 sm[65536];  // 128 KiB
    __hip_bfloat16* Asm = sm;
    __hip_bfloat16* Bsm = sm + 32768;

    const int nbx = N / PBN;
    const int nbm = M / PBM;
    const int sh = (nbm < 8) ? nbm : 8;
    const int id = blockIdx.x;
    const int wi = id % (sh * nbx);
    const int bm = ((id / (sh * nbx)) * sh + (wi % sh)) * PBM;
    const int bn = (wi / sh) * PBN;

    const int tid  = threadIdx.x;
    const int lane = tid & 63;
    const int w    = tid >> 6;
    const int wm   = w >> 2;
    const int wn   = w & 3;
    const int r15  = lane & 15;
    const int kg   = lane >> 4;

    const int nt = K / 64;

    const int rl = tid >> 3;
    const int g  = (tid & 7) ^ (rl & 7);
    const __hip_bfloat16* aS = A  + (size_t)(bm + rl) * K + g * 8;
    const __hip_bfloat16* bS = Bt + (size_t)(bn + rl) * K + g * 8;
    __hip_bfloat16* dA = Asm + tid * 8;
    __hip_bfloat16* dB = Bsm + tid * 8;

    auto stA = [&](int t, int h) {
        const int tc = (t < nt) ? t : (nt - 1);
        __hip_bfloat16* d = dA + ((t & 1) * 2 + h) * 8192;
        const __hip_bfloat16* s = aS + (size_t)(h * 128) * K + tc * 64;
        gld_lds16(s, d);
        gld_lds16(s + (size_t)64 * K, d + 4096);
    };
    auto stB = [&](int t, int h) {
        const int tc = (t < nt) ? t : (nt - 1);
        __hip_bfloat16* d = dB + ((t & 1) * 2 + h) * 8192;
        const __hip_bfloat16* s = bS + (size_t)(h * 128) * K + tc * 64;
        gld_lds16(s, d);
        gld_lds16(s + (size_t)64 * K, d + 4096);
    };

    const int x3    = (r15 & 7) << 3;
    const int kofs0 = (kg * 8) ^ x3;
    const int kofs1 = (32 + kg * 8) ^ x3;
    const __hip_bfloat16* Af0 = Asm + wm * 8192 + r15 * 64;
    const __hip_bfloat16* Bf0 = Bsm + (wn >> 1) * 8192 + (wn & 1) * 4096 + r15 * 64;
    const __hip_bfloat16* Af1 = Af0 + 16384;
    const __hip_bfloat16* Bf1 = Bf0 + 16384;

    f32x4 acc[8][4] = {};
    short8 af[8][2], bf[4][2];

    stA(0, 0); stA(0, 1); stB(0, 0); stB(0, 1); stA(1, 0); stA(1, 1);
    asm volatile("s_waitcnt vmcnt(4)" ::: "memory");
    __builtin_amdgcn_s_barrier();

    P8_KLOOP(Af0, Bf0, Af1, Bf1)

    asm volatile("s_waitcnt vmcnt(0)" ::: "memory");

    const int row0 = bm + wm * 128 + (lane >> 4) * 4;

    float brow[8][4];
    if (BROW) {
#pragma unroll
        for (int i = 0; i < 8; ++i)
#pragma unroll
            for (int r = 0; r < 4; ++r) brow[i][r] = bias[row0 + i * 16 + r];
    }
#pragma unroll
    for (int j = 0; j < 4; ++j) {
        const int col = bn + wn * 64 + j * 16 + r15;
        const float bv = BROW ? 0.0f : bias[col];
        const bool kp_col = ((col & 127) < 64);
#pragma unroll
        for (int i = 0; i < 8; ++i) {
#pragma unroll
            for (int r = 0; r < 4; ++r) {
                const int row = row0 + i * 16 + r;
                float v = acc[i][j][r] + (BROW ? brow[i][r] : bv);
                if (EPI == 1) v = elu1(v);
                else if (EPI == 2) {
                    const bool kp = BROW ? ((row & 127) < 64) : kp_col;
                    if (kp) v = elu1(v);
                }
                store_out(C + (size_t)row * N + col, v);
            }
        }
    }
}

// ---------------------------------------------------------------------------
// gemm3_ctx: kv-tile GEMM with FUSED ctx/ksum epilogue — kvT never hits HBM.
// K-loop identical to gemm_p8 (round-7 validated).  Epilogue:
//  1) v = acc + bu[j]; elu1 on K-rows ((j&127)<64); bf16 -> LDS Ltile[j][t]
//     (256x256 bf16 = 128 KiB, reuses sm), 16B-granule XOR swizzle
//     g' = (t>>3) ^ (j&7)  (read pattern = b128 bank baseline, conflict-free).
//  2) per wave (hh = w>>2, di = (w>>1)&1, ei = w&1): 32x32 ctx quadrant
//     ctx[d][e] += sum_t K[d][t]*V[e][t], 8 MFMA chains of K=32 over t=256;
//     ksum via ones-vector B (ei==0 waves), exactly ctx_mfma's trick.
//  3) atomicAdd into fp32 ctx/ksum (zeroed by prep).  Quantization path
//     (fp32->bf16->fp32-accum) identical to the old kvT/ctx_mfma pipeline.
// ---------------------------------------------------------------------------
__global__ __launch_bounds__(512, 2) void gemm3_ctx(
    const __hip_bfloat16* __restrict__ A,    // WuT [2048][256]
    const __hip_bfloat16* __restrict__ Bt,   // xdb [16384][256]
    const float* __restrict__ bias,          // bu [2048]
    float* __restrict__ ctx, float* __restrict__ ksum,
    int M, int N, int K)
{
    __shared__ alignas(16) __hip_bfloat16 sm[65536];  // 128 KiB
    __hip_bfloat16* Asm = sm;
    __hip_bfloat16* Bsm = sm + 32768;

    const int nbx = N / PBN;
    const int nbm = M / PBM;
    const int sh = (nbm < 8) ? nbm : 8;
    const int id = blockIdx.x;
    const int wi = id % (sh * nbx);
    const int bm = ((id / (sh * nbx)) * sh + (wi % sh)) * PBM;
    const int bn = (wi / sh) * PBN;

    const int tid  = threadIdx.x;
    const int lane = tid & 63;
    const int w    = tid >> 6;
    const int wm   = w >> 2;
    const int wn   = w & 3;
    const int r15  = lane & 15;
    const int kg   = lane >> 4;

    const int nt = K / 64;   // = 4

    const int rl = tid >> 3;
    const int g  = (tid & 7) ^ (rl & 7);
    const __hip_bfloat16* aS = A  + (size_t)(bm + rl) * K + g * 8;
    const __hip_bfloat16* bS = Bt + (size_t)(bn + rl) * K + g * 8;
    __hip_bfloat16* dA = Asm + tid * 8;
    __hip_bfloat16* dB = Bsm + tid * 8;

    auto stA = [&](int t, int h) {
        const int tc = (t < nt) ? t : (nt - 1);
        __hip_bfloat16* d = dA + ((t & 1) * 2 + h) * 8192;
        const __hip_bfloat16* s = aS + (size_t)(h * 128) * K + tc * 64;
        gld_lds16(s, d);
        gld_lds16(s + (size_t)64 * K, d + 4096);
    };
    auto stB = [&](int t, int h) {
        const int tc = (t < nt) ? t : (nt - 1);
        __hip_bfloat16* d = dB + ((t & 1) * 2 + h) * 8192;
        const __hip_bfloat16* s = bS + (size_t)(h * 128) * K + tc * 64;
        gld_lds16(s, d);
        gld_lds16(s + (size_t)64 * K, d + 4096);
    };

    const int x3    = (r15 & 7) << 3;
    const int kofs0 = (kg * 8) ^ x3;
    const int kofs1 = (32 + kg * 8) ^ x3;
    const __hip_bfloat16* Af0 = Asm + wm * 8192 + r15 * 64;
    const __hip_bfloat16* Bf0 = Bsm + (wn >> 1) * 8192 + (wn & 1) * 4096 + r15 * 64;
    const __hip_bfloat16* Af1 = Af0 + 16384;
    const __hip_bfloat16* Bf1 = Bf0 + 16384;

    f32x4 acc[8][4] = {};
    short8 af[8][2], bf[4][2];

    stA(0, 0); stA(0, 1); stB(0, 0); stB(0, 1); stA(1, 0); stA(1, 1);
    asm volatile("s_waitcnt vmcnt(4)" ::: "memory");
    __builtin_amdgcn_s_barrier();

    P8_KLOOP(Af0, Bf0, Af1, Bf1)

    asm volatile("s_waitcnt vmcnt(0)" ::: "memory");
    __syncthreads();   // all DMA (incl. dead tail dups) drained before reuse

    // ---- 1) bias + elu1(K-rows), bf16 -> Ltile[j][t] swizzled ----
    __hip_bfloat16* Lt = sm;
    {
        const int jb0 = wm * 128 + (lane >> 4) * 4;   // local j of frag rows
        float brow[8][4];
#pragma unroll
        for (int i = 0; i < 8; ++i)
#pragma unroll
            for (int r = 0; r < 4; ++r) brow[i][r] = bias[bm + jb0 + i * 16 + r];
#pragma unroll
        for (int i = 0; i < 8; ++i)
#pragma unroll
            for (int r = 0; r < 4; ++r) {
                const int j = jb0 + i * 16 + r;
                const bool kp = (j & 127) < 64;       // bm%256==0 -> local test ok
#pragma unroll
                for (int jj = 0; jj < 4; ++jj) {
                    const int t = wn * 64 + jj * 16 + r15;
                    float v = acc[i][jj][r] + brow[i][r];
                    if (kp) v = elu1(v);
                    Lt[j * 256 + (((t >> 3) ^ (j & 7)) * 8) + (t & 7)] =
                        __float2bfloat16(v);
                }
            }
    }
    __syncthreads();

    // ---- 2) ctx quadrant per wave ----
    const int hh = w >> 2, di = (w >> 1) & 1, ei = w & 1;
    const short one = (short)0x3F80;
    const short8 bfv = (r15 == 0)
        ? (short8){one, one, one, one, one, one, one, one}
        : (short8){0, 0, 0, 0, 0, 0, 0, 0};
    f32x4 cacc[2][2] = {};
    f32x4 kacc[2] = {};
#pragma unroll
    for (int ks = 0; ks < 8; ++ks) {
        short8 kf[2], vf[2];
#pragma unroll
        for (int i2 = 0; i2 < 2; ++i2) {
            const int jA = hh * 128 + di * 32 + i2 * 16 + r15;
            kf[i2] = *(const short8*)(Lt + jA * 256 + (((ks * 4 + kg) ^ (jA & 7)) * 8));
            const int jV = hh * 128 + 64 + ei * 32 + i2 * 16 + r15;
            vf[i2] = *(const short8*)(Lt + jV * 256 + (((ks * 4 + kg) ^ (jV & 7)) * 8));
        }
#pragma unroll
        for (int i2 = 0; i2 < 2; ++i2) {
#pragma unroll
            for (int j2 = 0; j2 < 2; ++j2)
                cacc[i2][j2] = __builtin_amdgcn_mfma_f32_16x16x32_bf16(kf[i2], vf[j2], cacc[i2][j2], 0, 0, 0);
            if (ei == 0)
                kacc[i2] = __builtin_amdgcn_mfma_f32_16x16x32_bf16(kf[i2], bfv, kacc[i2], 0, 0, 0);
        }
    }

    // ---- 3) atomics into ctx/ksum ----
    const int bh = ((bn >> 12) << 4) + (bm >> 7) + hh;  // b*16 + h
    float* cd = ctx + (size_t)bh * 4096;
    const int q4 = lane >> 4;
#pragma unroll
    for (int i2 = 0; i2 < 2; ++i2)
#pragma unroll
        for (int j2 = 0; j2 < 2; ++j2)
#pragma unroll
            for (int r = 0; r < 4; ++r) {
                const int d = di * 32 + i2 * 16 + q4 * 4 + r;
                const int e = ei * 32 + j2 * 16 + r15;
                atomicAdd(cd + d * 64 + e, cacc[i2][j2][r]);
            }
    if (ei == 0 && r15 == 0) {
#pragma unroll
        for (int i2 = 0; i2 < 2; ++i2)
#pragma unroll
            for (int r = 0; r < 4; ++r)
                atomicAdd(ksum + bh * 64 + di * 32 + i2 * 16 + q4 * 4 + r,
                          kacc[i2][r]);
    }
}

#undef RDA
#undef RDB
#undef MM
#undef SB0

// ---------------------------------------------------------------------------
// OLD 128x128 ring GEMM (hardware-validated round 1) — kept for xd (N=256).
// ---------------------------------------------------------------------------
#define BM 128
#define BN 128
#define BK 32
#define NBUF 5

template<int EPI, bool BROW, typename OT>
__global__ __launch_bounds__(256) void gemm_bf16(
    const __hip_bfloat16* __restrict__ A,
    const __hip_bfloat16* __restrict__ Bt,
    const float* __restrict__ bias,
    OT* __restrict__ C,
    OT* __restrict__ C2,
    int M, int N, int K)
{
    __shared__ alignas(16) __hip_bfloat16 As[NBUF * BM * BK];
    __shared__ alignas(16) __hip_bfloat16 Bs[NBUF * BN * BK];

    const int nbx = N / BN;
    const int id = blockIdx.x;
    const int strip = id / (8 * nbx);
    const int wi = id % (8 * nbx);
    const int bm = (strip * 8 + (wi & 7)) * BM;
    const int bn = (wi >> 3) * BN;

    const int tid  = threadIdx.x;
    const int lane = tid & 63;
    const int wm   = (tid >> 7) * 64;
    const int wn   = ((tid >> 6) & 1) * 64;
    const int r15  = lane & 15;
    const int kg   = lane >> 4;

    f32x4 acc[4][4] = {};

    const int c0 = tid, c1 = tid + 256;
    const __hip_bfloat16* a0 = A  + (size_t)(bm + (c0 >> 2)) * K + (c0 & 3) * 8;
    const __hip_bfloat16* a1 = A  + (size_t)(bm + (c1 >> 2)) * K + (c1 & 3) * 8;
    const __hip_bfloat16* b0 = Bt + (size_t)(bn + (c0 >> 2)) * K + (c0 & 3) * 8;
    const __hip_bfloat16* b1 = Bt + (size_t)(bn + (c1 >> 2)) * K + (c1 & 3) * 8;

    const int nk = K / BK;

    auto stage = [&](int t) {
        const int buf = t % NBUF;
        __hip_bfloat16* Ad = As + buf * (BM * BK);
        __hip_bfloat16* Bd = Bs + buf * (BN * BK);
        const int k0 = t * BK;
        gld_lds16(a0 + k0, Ad + c0 * 8);
        gld_lds16(a1 + k0, Ad + c1 * 8);
        gld_lds16(b0 + k0, Bd + c0 * 8);
        gld_lds16(b1 + k0, Bd + c1 * 8);
    };

    stage(0); stage(1); stage(2);

    for (int t = 0; t < nk; ++t) {
        if (t + 3 < nk) {
            stage(t + 3);
            asm volatile("s_waitcnt vmcnt(12)\ns_barrier" ::: "memory");
        } else if (t + 2 < nk) {
            asm volatile("s_waitcnt vmcnt(8)\ns_barrier" ::: "memory");
        } else if (t + 1 < nk) {
            asm volatile("s_waitcnt vmcnt(4)\ns_barrier" ::: "memory");
        } else {
            asm volatile("s_waitcnt vmcnt(0)\ns_barrier" ::: "memory");
        }

        const __hip_bfloat16* Asb = As + (t % NBUF) * (BM * BK);
        const __hip_bfloat16* Bsb = Bs + (t % NBUF) * (BN * BK);

        short8 af[4], bf[4];
#pragma unroll
        for (int i = 0; i < 4; ++i) {
            af[i] = *(const short8*)(Asb + (wm + i * 16 + r15) * BK + kg * 8);
            bf[i] = *(const short8*)(Bsb + (wn + i * 16 + r15) * BK + kg * 8);
        }
#pragma unroll
        for (int i = 0; i < 4; ++i)
#pragma unroll
            for (int j = 0; j < 4; ++j)
                acc[i][j] = __builtin_amdgcn_mfma_f32_16x16x32_bf16(af[i], bf[j], acc[i][j], 0, 0, 0);
    }

    const int row0 = bm + wm + (lane >> 4) * 4;

    if (EPI == 3) {
        const bool qreg = (bn < 1024);
#pragma unroll
        for (int j = 0; j < 4; ++j) {
            const int col = bn + wn + j * 16 + r15;
            const float bv = bias[col];
#pragma unroll
            for (int i = 0; i < 4; ++i)
#pragma unroll
                for (int r = 0; r < 4; ++r) {
                    const int row = row0 + i * 16 + r;
                    float v = acc[i][j][r] + bv;
                    if (qreg) {
                        store_out(C + (size_t)row * 1024 + col, elu1(v));
                    } else {
                        store_out(C2 + (size_t)row * 256 + (col - 1024), v);
                    }
                }
        }
        return;
    }

    float brow[4][4];
    if (BROW) {
#pragma unroll
        for (int i = 0; i < 4; ++i)
#pragma unroll
            for (int r = 0; r < 4; ++r) brow[i][r] = bias[row0 + i * 16 + r];
    }
#pragma unroll
    for (int j = 0; j < 4; ++j) {
        const int col = bn + wn + j * 16 + r15;
        const float bv = BROW ? 0.0f : bias[col];
        const bool kp_col = ((col & 127) < 64);
#pragma unroll
        for (int i = 0; i < 4; ++i) {
#pragma unroll
            for (int r = 0; r < 4; ++r) {
                const int row = row0 + i * 16 + r;
                float v = acc[i][j][r] + (BROW ? brow[i][r] : bv);
                if (EPI == 1) v = elu1(v);
                else if (EPI == 2) {
                    const bool kp = BROW ? ((row & 127) < 64) : kp_col;
                    if (kp) v = elu1(v);
                }
                store_out(C + (size_t)row * N + col, v);
            }
        }
    }
}

// ---------------------------------------------------------------------------
// prep: fused preprocessing — cast x->bf16, 4 weight transpose-casts, and
// zeroing of ctx/ksum — one dispatch, branch by block range.
// ---------------------------------------------------------------------------
__device__ __forceinline__ void tcast_body(
    const float* __restrict__ W, __hip_bfloat16* __restrict__ Wt,
    int K, int N, int bx, int by, int tid, float (*t)[33])
{
    const int n0 = bx * 32, k0 = by * 32;
    const int c = tid & 31, r = tid >> 5;
#pragma unroll
    for (int rr = r; rr < 32; rr += 8)
        t[rr][c] = W[(size_t)(k0 + rr) * N + n0 + c];
    __syncthreads();
#pragma unroll
    for (int rr = r; rr < 32; rr += 8)
        Wt[(size_t)(n0 + rr) * K + k0 + c] = __float2bfloat16(t[c][rr]);
}

__global__ __launch_bounds__(256) void prep(
    const float* __restrict__ x,
    const float* __restrict__ Wq, const float* __restrict__ Wd,
    const float* __restrict__ Wu, const float* __restrict__ Wo,
    __hip_bfloat16* __restrict__ xb,
    __hip_bfloat16* __restrict__ WqdT, __hip_bfloat16* __restrict__ WuT,
    __hip_bfloat16* __restrict__ WoT,
    float* __restrict__ zbase)
{
    __shared__ float t[32][33];
    const int id = blockIdx.x;
    const int tid = threadIdx.x;

    if (id < 8192) {                       // cast x -> xb (bf16x8)
        const int i = (id * 256 + tid) * 8;
        float4 v0 = *(const float4*)(x + i);
        float4 v1 = *(const float4*)(x + i + 4);
        __hip_bfloat16 tt[8];
        tt[0] = __float2bfloat16(v0.x); tt[1] = __float2bfloat16(v0.y);
        tt[2] = __float2bfloat16(v0.z); tt[3] = __float2bfloat16(v0.w);
        tt[4] = __float2bfloat16(v1.x); tt[5] = __float2bfloat16(v1.y);
        tt[6] = __float2bfloat16(v1.z); tt[7] = __float2bfloat16(v1.w);
        *(short8*)(xb + i) = *(const short8*)tt;
    } else if (id < 8192 + 1024) {         // Wq [1024,1024] -> WqdT
        const int u = id - 8192;
        tcast_body(Wq, WqdT, D_, D_, u & 31, u >> 5, tid, t);
    } else if (id < 8192 + 1280) {         // Wd [1024,256] -> WqdT+1024*1024
        const int u = id - (8192 + 1024);
        tcast_body(Wd, WqdT + (size_t)D_ * D_, D_, R_, u & 7, u >> 3, tid, t);
    } else if (id < 8192 + 1792) {         // Wu [256,2048] -> WuT
        const int u = id - (8192 + 1280);
        tcast_body(Wu, WuT, R_, TWO_D_, u & 63, u >> 6, tid, t);
    } else if (id < 8192 + 2816) {         // Wo [1024,1024] -> WoT
        const int u = id - (8192 + 1792);
        tcast_body(Wo, WoT, D_, D_, u & 31, u >> 5, tid, t);
    } else {                               // zero ctx+ksum (266240 floats)
        const int u = id - (8192 + 2816);
        const int i = (u * 256 + tid) * 8;
        float4 z = {0.f, 0.f, 0.f, 0.f};
        *(float4*)(zbase + i) = z;
        *(float4*)(zbase + i + 4) = z;
    }
}

// ---------------------------------------------------------------------------
__global__ __launch_bounds__(256) void pack_ctx(
    const float* __restrict__ ctx, __hip_bfloat16* __restrict__ ctxT)
{
    __shared__ float L[64 * 65];
    const int bh = blockIdx.x;
    const int tid = threadIdx.x;
#pragma unroll
    for (int r = 0; r < 16; ++r) {
        const int idx = r * 256 + tid;
        L[(idx >> 6) * 65 + (idx & 63)] = ctx[(size_t)bh * 4096 + idx];
    }
    __syncthreads();
#pragma unroll
    for (int r = 0; r < 16; ++r) {
        const int idx = r * 256 + tid;
        ctxT[(size_t)bh * 4096 + idx] =
            __float2bfloat16(L[(idx & 63) * 65 + (idx >> 6)]);
    }
}

// ---------------------------------------------------------------------------
// out_mfma: out[t][h*64+e] = z_t * sum_d q[t][d] * ctx[d][e]
// ---------------------------------------------------------------------------
__global__ __launch_bounds__(256) void out_mfma(
    const __hip_bfloat16* __restrict__ qb, const __hip_bfloat16* __restrict__ ctxT,
    const float* __restrict__ ksum, __hip_bfloat16* __restrict__ outb)
{
    __shared__ alignas(16) unsigned char As[256 * 128];
    __shared__ alignas(16) unsigned char Bs[64 * 128];
    __shared__ float ksumL[64];
    __shared__ float zbuf[256];

    const int bh = blockIdx.x >> 4;
    const int tile = blockIdx.x & 15;
    const int b = bh >> 4;
    const int h = bh & 15;
    const int tid = threadIdx.x;
    const int lane = tid & 63;
    const int w = tid >> 6;
    const int r15 = lane & 15;
    const int kg  = lane >> 4;

    const size_t trow0 = (size_t)b * T_ + (size_t)tile * 256;

#pragma unroll
    for (int r = 0; r < 8; ++r) {
        const int c = r * 256 + tid;
        const int row = c >> 3, slot = c & 7, u = slot ^ (row & 7);
        gld_lds16(qb + (trow0 + row) * D_ + h * 64 + u * 8, As + c * 16);
    }
#pragma unroll
    for (int r = 0; r < 2; ++r) {
        const int c = r * 256 + tid;
        const int row = c >> 3, slot = c & 7, u = slot ^ (row & 7);
        gld_lds16(ctxT + (size_t)bh * 4096 + row * 64 + u * 8, Bs + c * 16);
    }
    if (tid < 64) ksumL[tid] = ksum[bh * 64 + tid];
    __syncthreads();

    short8 af[4][2], bf[4][2];
#pragma unroll
    for (int i = 0; i < 4; ++i)
#pragma unroll
        for (int s = 0; s < 2; ++s) {
            const int m = w * 64 + i * 16 + r15;
            const int n = i * 16 + r15;
            const int uk = s * 4 + kg;
            af[i][s] = *(const short8*)(As + m * 128 + ((uk ^ (m & 7)) * 16));
            bf[i][s] = *(const short8*)(Bs + n * 128 + ((uk ^ (n & 7)) * 16));
        }

    f32x4 acc[4][4] = {};
#pragma unroll
    for (int s = 0; s < 2; ++s)
#pragma unroll
        for (int i = 0; i < 4; ++i)
#pragma unroll
            for (int j = 0; j < 4; ++j)
                acc[i][j] = __builtin_amdgcn_mfma_f32_16x16x32_bf16(af[i][s], bf[j][s], acc[i][j], 0, 0, 0);

    float dsum[4];
#pragma unroll
    for (int i = 0; i < 4; ++i) {
        float s0 = 0.0f;
#pragma unroll
        for (int s = 0; s < 2; ++s)
#pragma unroll
            for (int j8 = 0; j8 < 8; ++j8)
                s0 += bf2f(af[i][s][j8]) * ksumL[s * 32 + kg * 8 + j8];
        s0 += __shfl_xor(s0, 16);
        s0 += __shfl_xor(s0, 32);
        dsum[i] = s0;
    }
    if (lane < 16) {
#pragma unroll
        for (int i = 0; i < 4; ++i)
            zbuf[w * 64 + i * 16 + lane] = 1.0f / (dsum[i] + 1e-6f);
    }
    __syncthreads();

    const int q4 = lane >> 4;
#pragma unroll
    for (int i = 0; i < 4; ++i) {
#pragma unroll
        for (int r = 0; r < 4; ++r) {
            const int m = w * 64 + i * 16 + q4 * 4 + r;
            const float z = zbuf[m];
#pragma unroll
            for (int j = 0; j < 4; ++j) {
                outb[(trow0 + m) * D_ + h * 64 + j * 16 + r15] =
                    __float2bfloat16(acc[i][j][r] * z);
            }
        }
    }
}

// ---------------------------------------------------------------------------
extern "C" void kernel_launch(void* const* d_in, const int* in_sizes, int n_in,
                              void* d_out, int out_size, void* d_ws, size_t ws_size,
                              hipStream_t stream) {
    const float* x  = (const float*)d_in[0];
    const float* Wq = (const float*)d_in[1];
    const float* bq = (const float*)d_in[2];
    const float* Wd = (const float*)d_in[3];
    const float* bd = (const float*)d_in[4];
    const float* Wu = (const float*)d_in[5];
    const float* bu = (const float*)d_in[6];
    const float* Wo = (const float*)d_in[7];
    const float* bo = (const float*)d_in[8];
    float* out = (float*)d_out;

    __hip_bfloat16* xb    = (__hip_bfloat16*)d_ws;            // BT*D
    __hip_bfloat16* WqdT  = xb    + (size_t)BT_ * D_;         // [1280][1024]
    __hip_bfloat16* WuT   = WqdT  + (size_t)1280 * D_;        // [2048][256]
    __hip_bfloat16* WoT   = WuT   + (size_t)TWO_D_ * R_;      // [1024][1024]
    __hip_bfloat16* xdb   = WoT   + (size_t)D_ * D_;          // BT*R
    __hip_bfloat16* kvT   = xdb   + (size_t)BT_ * R_;         // (unused now)
    __hip_bfloat16* qb    = kvT   + (size_t)TWO_D_ * BT_;     // BT*D
    float* bias_qd = (float*)(qb + (size_t)BT_ * D_);         // 1280 (unused)
    float* ctx  = bias_qd + 1280;                             // 64*4096
    float* ksum = ctx + (size_t)B_ * H_ * DH_ * DH_;          // 64*64
    __hip_bfloat16* ctxT = (__hip_bfloat16*)(ksum + B_ * H_ * DH_);  // 64*4096
    __hip_bfloat16* outb = xb;   // alias: xb dead after q/xd GEMMs

    // fused preprocessing: cast + 4 transposes + zero(ctx,ksum)
    prep<<<8192 + 2816 + 130, 256, 0, stream>>>(
        x, Wq, Wd, Wu, Wo, xb, WqdT, WuT, WoT, ctx);

    // 1) xd = x @ Wd + bd    (128^2 ring; grid 256 = 1 block/CU)
    gemm_bf16<0, false, __hip_bfloat16><<<(BT_ / BM) * (R_ / BN), 256, 0, stream>>>(
        xb, WqdT + (size_t)D_ * D_, bd, xdb, nullptr, BT_, R_, D_);
    // 2) q = elu1(x @ Wq + bq)   (256^2 8-phase; grid 256; nt=16)
    gemm_p8<1, false, __hip_bfloat16><<<(BT_ / PBM) * (D_ / PBN), 512, 0, stream>>>(
        xb, WqdT, bq, qb, BT_, D_, D_);
    // 3+4) kv GEMM fused with ctx/ksum accumulation (grid 512; nt=4)
    gemm3_ctx<<<(TWO_D_ / PBM) * (BT_ / PBN), 512, 0, stream>>>(
        WuT, xdb, bu, ctx, ksum, TWO_D_, BT_, R_);
    // 5) pack ctx -> bf16 transposed
    pack_ctx<<<64, 256, 0, stream>>>(ctx, ctxT);
    // 6) out = z * (q @ ctx)
    out_mfma<<<64 * 16, 256, 0, stream>>>(qb, ctxT, ksum, outb);
    // 7) final = outb @ Wo + bo   (256^2 8-phase; grid 256; nt=16)
    gemm_p8<0, false, float><<<(BT_ / PBM) * (D_ / PBN), 512, 0, stream>>>(
        outb, WoT, bo, out, BT_, D_, D_);
}